// Round 6
// baseline (257.812 us; speedup 1.0000x reference)
//
#include <hip/hip_runtime.h>
#include <hip/hip_bf16.h>

// RandomProjectionQuantizer — runtime-calibrated per-row MFMA screening (R6).
//  x:(16,2048,320) f32, mask:(16,2048) i32 (exactly 16384 ones),
//  W:(16,320) f32, codebook:(8192,16) f32 -> scalar int32 label
//
//  Screening folds the FULL distance into the MFMA dot (R5-verified):
//    A~ = [t(16), 1, 1, h1, h2, 0...]   (h1+h2 = bf16-split of ||t||^2)
//    C~ = [-2c(16), g1, g2, 1, 1, 0...] (g1+g2 = bf16-split of ||c||^2)
//  -> every output element is a genuine full d2 value (no col attribution).
//  Row attribution is CALIBRATED at runtime: one MFMA with A rows (r+1)e0,
//  B rows e0 gives each lane its output-row index per reg. Per-row minima
//  then gate an exact f32 rescore of ~tens of rows.

#define NMASK   16384
#define D       320
#define CDIM    16
#define NCODES  8192
#define EPS_C   0.0117f      // 1.5 * 2^-7  (bf16 RNE dot-error coefficient)
#define EPS_ABS 0.02f

typedef __attribute__((ext_vector_type(8))) short short8;
typedef __attribute__((ext_vector_type(4))) float f32x4;

__device__ inline unsigned int encf(float f) {
  unsigned int u = __float_as_uint(f);
  return (u & 0x80000000u) ? ~u : (u | 0x80000000u);
}
__device__ inline float decf(unsigned int u) {
  unsigned int b = (u & 0x80000000u) ? (u & 0x7fffffffu) : ~u;
  return __uint_as_float(b);
}
__device__ inline unsigned short f2bf(float f) {   // RNE f32->bf16
  unsigned int u = __float_as_uint(f);
  unsigned int r = u + 0x7fffu + ((u >> 16) & 1u);
  return (unsigned short)(r >> 16);
}
__device__ inline float bf2f(unsigned short h) {
  return __uint_as_float(((unsigned int)h) << 16);
}

// shared projection chain: 4 lanes/row (chunk ch of 80), butterfly combine.
// Bit-identical between project and rescore (R5-verified).
__device__ inline void proj_row(const float* __restrict__ x,
                                const float* __restrict__ W,
                                int row, int ch, float pd[16]) {
#pragma unroll
  for (int c = 0; c < 16; ++c) pd[c] = 0.f;
  const float4* xp = (const float4*)(x + (size_t)row * D + ch * 80);
#pragma unroll 4
  for (int j = 0; j < 20; ++j) {
    float4 xv = xp[j];
#pragma unroll
    for (int c = 0; c < 16; ++c) {
      const float4 wv = *(const float4*)(W + c * D + ch * 80 + j * 4);
      float acc = fmaf(xv.x, wv.x, pd[c]);
      acc = fmaf(xv.y, wv.y, acc);
      acc = fmaf(xv.z, wv.z, acc);
      pd[c] = fmaf(xv.w, wv.w, acc);
    }
  }
#pragma unroll
  for (int c = 0; c < 16; ++c) {
    pd[c] += __shfl_xor(pd[c], 1);
    pd[c] += __shfl_xor(pd[c], 2);
  }
}

// ---------------- Kernel 1: prep (80 blocks x 512) ---------------------------
__global__ __launch_bounds__(512) void prep_kernel(
    const int* __restrict__ mask, const float* __restrict__ cbk,
    unsigned int* __restrict__ chunksum, int* __restrict__ chunkpref,
    float* __restrict__ c2, unsigned short* __restrict__ cbf32,
    float* __restrict__ pmax_c2, unsigned long long* __restrict__ key,
    unsigned int* __restrict__ prepctr) {
  __shared__ int lastf;
  int tid = threadIdx.x, bid = (int)blockIdx.x;
  if (bid < 64) {                                   // 64 blocks x 8 waves = 512 chunks
    int wv = tid >> 6, lane = tid & 63;
    int c = bid * 8 + wv;
    int m = mask[c * 64 + lane];
    unsigned long long bal = __ballot(m != 0);
    if (lane == 0) atomicExch(&chunksum[c], (unsigned int)__popcll(bal));
  } else {                                          // 16 blocks x 512 codes
    __shared__ float sm[512];
    int b = bid - 64;
    int k = b * 512 + tid;
    const float4* p = (const float4*)(cbk + (long)k * CDIM);
    float s = 0.f; unsigned short nb[16];
#pragma unroll
    for (int q = 0; q < 4; ++q) {
      float4 v = p[q];
      s = fmaf(v.x, v.x, s); s = fmaf(v.y, v.y, s);
      s = fmaf(v.z, v.z, s); s = fmaf(v.w, v.w, s);
      nb[q*4+0] = f2bf(-2.0f * v.x); nb[q*4+1] = f2bf(-2.0f * v.y);
      nb[q*4+2] = f2bf(-2.0f * v.z); nb[q*4+3] = f2bf(-2.0f * v.w);
    }
    c2[k] = s;
    unsigned short g1 = f2bf(s);
    unsigned short g2 = f2bf(s - bf2f(g1));
    uint4 pk0, pk1, pk2, pk3;
    pk0.x = (unsigned int)nb[0]  | ((unsigned int)nb[1]  << 16);
    pk0.y = (unsigned int)nb[2]  | ((unsigned int)nb[3]  << 16);
    pk0.z = (unsigned int)nb[4]  | ((unsigned int)nb[5]  << 16);
    pk0.w = (unsigned int)nb[6]  | ((unsigned int)nb[7]  << 16);
    pk1.x = (unsigned int)nb[8]  | ((unsigned int)nb[9]  << 16);
    pk1.y = (unsigned int)nb[10] | ((unsigned int)nb[11] << 16);
    pk1.z = (unsigned int)nb[12] | ((unsigned int)nb[13] << 16);
    pk1.w = (unsigned int)nb[14] | ((unsigned int)nb[15] << 16);
    pk2.x = (unsigned int)g1 | ((unsigned int)g2 << 16); // dims 16,17: g1,g2
    pk2.y = 0x3F803F80u;                                 // dims 18,19: 1,1
    pk2.z = 0u; pk2.w = 0u;
    pk3.x = 0u; pk3.y = 0u; pk3.z = 0u; pk3.w = 0u;
    uint4* dst = (uint4*)(cbf32 + (long)k * 32);
    dst[0] = pk0; dst[1] = pk1; dst[2] = pk2; dst[3] = pk3;
    if (b == 0 && tid == 0) key[0] = 0xFFFFFFFFFFFFFFFFull;
    sm[tid] = s; __syncthreads();
    for (int st = 256; st > 0; st >>= 1) {
      if (tid < st) sm[tid] = fmaxf(sm[tid], sm[tid + st]);
      __syncthreads();
    }
    if (tid == 0) pmax_c2[b] = sm[0];
  }
  __threadfence();
  __syncthreads();
  if (tid == 0) lastf = (atomicAdd(prepctr, 1u) == 79u) ? 1 : 0;
  __syncthreads();
  if (lastf) {                                      // last block: 512-chunk scan
    __shared__ int a[512], bb[512];
    a[tid] = (int)atomicAdd(&chunksum[tid], 0u);
    __syncthreads();
    int *src = a, *dst2 = bb;
    for (int off = 1; off < 512; off <<= 1) {
      dst2[tid] = src[tid] + (tid >= off ? src[tid - off] : 0);
      __syncthreads();
      int* t = src; src = dst2; dst2 = t;
    }
    chunkpref[tid] = (tid == 0) ? 0 : src[tid - 1];
  }
}

// ---------------- Kernel 2: project (512 blocks x 256) -----------------------
__global__ __launch_bounds__(256) void project_kernel(
    const float* __restrict__ x, const int* __restrict__ mask,
    const int* __restrict__ chunkpref, const float* __restrict__ W,
    unsigned short* __restrict__ tbf32, float* __restrict__ t2arr,
    int* __restrict__ origrow) {
  __shared__ unsigned long long mb;
  int tid = threadIdx.x, bid = (int)blockIdx.x;
  int base = bid * 64;
  if (tid < 64) {
    int m = mask[base + tid];
    unsigned long long bal = __ballot(m != 0);
    if (tid == 0) mb = bal;
  }
  __syncthreads();
  unsigned long long B0 = mb;
  int r = tid >> 2, ch = tid & 3;
  int row = base + r;
  int m = (int)((B0 >> r) & 1ull);
  if (!m) return;
  float pd[16];
  proj_row(x, W, row, ch, pd);
  if (ch == 0) {
    int rank = chunkpref[bid] + __popcll(B0 & ((1ull << r) - 1ull));
    float t2 = 0.f;
#pragma unroll
    for (int c = 0; c < 16; ++c) t2 = fmaf(pd[c], pd[c], t2);
    t2arr[rank] = t2;
    origrow[rank] = row;
    unsigned short tb[16];
#pragma unroll
    for (int c = 0; c < 16; ++c) tb[c] = f2bf(pd[c]);
    unsigned short h1 = f2bf(t2);
    unsigned short h2 = f2bf(t2 - bf2f(h1));
    uint4 pk0, pk1, pk2, pk3;
    pk0.x = (unsigned int)tb[0]  | ((unsigned int)tb[1]  << 16);
    pk0.y = (unsigned int)tb[2]  | ((unsigned int)tb[3]  << 16);
    pk0.z = (unsigned int)tb[4]  | ((unsigned int)tb[5]  << 16);
    pk0.w = (unsigned int)tb[6]  | ((unsigned int)tb[7]  << 16);
    pk1.x = (unsigned int)tb[8]  | ((unsigned int)tb[9]  << 16);
    pk1.y = (unsigned int)tb[10] | ((unsigned int)tb[11] << 16);
    pk1.z = (unsigned int)tb[12] | ((unsigned int)tb[13] << 16);
    pk1.w = (unsigned int)tb[14] | ((unsigned int)tb[15] << 16);
    pk2.x = 0x3F803F80u;                                 // dims 16,17: 1,1
    pk2.y = (unsigned int)h1 | ((unsigned int)h2 << 16); // dims 18,19: h1,h2
    pk2.z = 0u; pk2.w = 0u;
    pk3.x = 0u; pk3.y = 0u; pk3.z = 0u; pk3.w = 0u;
    uint4* dst = (uint4*)(tbf32 + (long)rank * 32);
    dst[0] = pk0; dst[1] = pk1; dst[2] = pk2; dst[3] = pk3;
  }
}

// ---------------- Kernel 3: calibrated per-row MFMA screening + gate ---------
// 512 blocks x 1024 threads; block = strip of 32 ranks; wave w = seg of 512
// codes. Runtime calibration: A rows (r+1)e0, B rows e0 -> cal[j] = sigma+1,
// the output-row index of this lane's reg j. No layout assumptions.
// Ticket-gated last block computes T and the candidate row list.
__global__ __launch_bounds__(1024) void phase1_kernel(
    const unsigned short* __restrict__ tbf32,
    const unsigned short* cbf32,                    // no restrict: aliases candlist
    const float* __restrict__ t2arr,
    const float* __restrict__ pmax_c2,
    unsigned int* __restrict__ rowmin_u,
    unsigned int* __restrict__ p1ctr,
    unsigned int* __restrict__ candcount,
    int* candlist) {
  __shared__ unsigned int rml[16 * 33];             // per-wave padded rowmin
  __shared__ float sT[1024];
  __shared__ int lastf;
  int tid = threadIdx.x;
  int w = tid >> 6, l = tid & 63, lr = l & 15, g = l >> 4;
  int strip = (int)blockIdx.x;
  int row0 = strip * 32;

  for (int i = tid; i < 16 * 33; i += 1024) rml[i] = 0xFFFFFFFFu;
  __syncthreads();

  const f32x4 zero = {0.f, 0.f, 0.f, 0.f};
  // --- calibration MFMA: learn sigma(lane, reg) = output row index ---
  short8 calA = {0,0,0,0,0,0,0,0}, calB = {0,0,0,0,0,0,0,0};
  if (g == 0) {
    calA[0] = (short)f2bf((float)(lr + 1));
    calB[0] = (short)0x3F80;                        // bf16 1.0
  }
  f32x4 cal = __builtin_amdgcn_mfma_f32_16x16x32_bf16(calA, calB, zero, 0, 0, 0);
  int rid[4];
#pragma unroll
  for (int j = 0; j < 4; ++j) {
    int v = (int)(cal[j] + 0.5f) - 1;
    rid[j] = v < 0 ? 0 : (v > 15 ? 15 : v);
  }

  const short8 a0 = *(const short8*)(tbf32 + (long)(row0 + lr) * 32 + g * 8);
  const short8 a1 = *(const short8*)(tbf32 + (long)(row0 + 16 + lr) * 32 + g * 8);
  f32x4 rmin0 = {3.4e38f, 3.4e38f, 3.4e38f, 3.4e38f};
  f32x4 rmin1 = rmin0;
  int code0 = w * 512;
#pragma unroll 2
  for (int t = 0; t < 32; ++t) {
    int code = code0 + t * 16 + lr;
    short8 b = *(const short8*)(cbf32 + (long)code * 32 + g * 8);
    f32x4 d0 = __builtin_amdgcn_mfma_f32_16x16x32_bf16(a0, b, zero, 0, 0, 0);
    f32x4 d1 = __builtin_amdgcn_mfma_f32_16x16x32_bf16(a1, b, zero, 0, 0, 0);
#pragma unroll
    for (int j = 0; j < 4; ++j) {
      rmin0[j] = fminf(rmin0[j], d0[j]);
      rmin1[j] = fminf(rmin1[j], d1[j]);
    }
  }
  unsigned int* mywave = &rml[w * 33];
#pragma unroll
  for (int j = 0; j < 4; ++j) {
    atomicMin(&mywave[rid[j]],      encf(rmin0[j]));
    atomicMin(&mywave[16 + rid[j]], encf(rmin1[j]));
  }
  __syncthreads();
  if (tid < 32) {                                   // combine 16 waves -> global
    unsigned int mn = 0xFFFFFFFFu;
#pragma unroll
    for (int ww = 0; ww < 16; ++ww) mn = min(mn, rml[ww * 33 + tid]);
    atomicExch(&rowmin_u[row0 + tid], mn);
  }
  __threadfence();
  __syncthreads();
  if (tid == 0) lastf = (atomicAdd(p1ctr, 1u) == (unsigned int)gridDim.x - 1u) ? 1 : 0;
  __syncthreads();
  if (lastf) {                                      // gate: T and candidate rows
    float c2m = 0.f;
#pragma unroll
    for (int i = 0; i < 16; ++i) c2m = fmaxf(c2m, pmax_c2[i]);
    float Tl = 3.4e38f;
    for (int i = tid; i < NMASK; i += 1024) {
      float a = decf(atomicAdd(&rowmin_u[i], 0u));  // coherent read
      float e = fmaf(EPS_C, sqrtf(t2arr[i] * c2m), EPS_ABS);
      Tl = fminf(Tl, a + e);                        // NaN a -> ignored
    }
    sT[tid] = Tl; __syncthreads();
    for (int st = 512; st > 0; st >>= 1) {
      if (tid < st) sT[tid] = fminf(sT[tid], sT[tid + st]);
      __syncthreads();
    }
    float T = sT[0];
    for (int i = tid; i < NMASK; i += 1024) {
      float a = decf(atomicAdd(&rowmin_u[i], 0u));
      float e = fmaf(EPS_C, sqrtf(t2arr[i] * c2m), EPS_ABS);
      if (!(a - e > T)) {                           // NaN-safe: NaN -> candidate
        unsigned int pos = atomicAdd(candcount, 1u);
        candlist[pos] = i;
      }
    }
  }
}

// ---------------- Kernel 4: exact rescore of candidate rows + emit -----------
// 256 blocks x 256; wave handles one candidate row per iteration.
__global__ __launch_bounds__(256) void rescore_kernel(
    const float* __restrict__ x, const float* __restrict__ W,
    const float* __restrict__ cbk, const float* __restrict__ c2,
    const int* __restrict__ origrow, const unsigned int* __restrict__ candcount,
    const int* candlist, unsigned long long* __restrict__ key,
    unsigned int* __restrict__ resctr, int* __restrict__ out) {
  int tid = threadIdx.x, bid = (int)blockIdx.x;
  int l = tid & 63, ch = l & 3;
  int nc = (int)candcount[0];
  for (int idx = bid * 4 + (tid >> 6); idx < nc; idx += 1024) {
    int r = candlist[idx];
    int row = origrow[r];
    float pd[16];
    proj_row(x, W, row, ch, pd);                    // bit-identical to project
    float t2 = 0.f, tm[16];
#pragma unroll
    for (int c = 0; c < 16; ++c) t2 = fmaf(pd[c], pd[c], t2);
#pragma unroll
    for (int c = 0; c < 16; ++c) tm[c] = -2.0f * pd[c];
    float minv = 3.4e38f; int mink = 0;
    for (int j = 0; j < 128; ++j) {                 // 128 codes per lane
      int code = j * 64 + l;
      const float4* cp = (const float4*)(cbk + (long)code * CDIM);
      float4 c0 = cp[0], c1 = cp[1], c2v4 = cp[2], c3 = cp[3];
      float acc = fmaf(tm[0],  c0.x, c2[code]);
      acc = fmaf(tm[1],  c0.y, acc);   acc = fmaf(tm[2],  c0.z, acc);
      acc = fmaf(tm[3],  c0.w, acc);   acc = fmaf(tm[4],  c1.x, acc);
      acc = fmaf(tm[5],  c1.y, acc);   acc = fmaf(tm[6],  c1.z, acc);
      acc = fmaf(tm[7],  c1.w, acc);   acc = fmaf(tm[8],  c2v4.x, acc);
      acc = fmaf(tm[9],  c2v4.y, acc); acc = fmaf(tm[10], c2v4.z, acc);
      acc = fmaf(tm[11], c2v4.w, acc); acc = fmaf(tm[12], c3.x, acc);
      acc = fmaf(tm[13], c3.y, acc);   acc = fmaf(tm[14], c3.z, acc);
      acc = fmaf(tm[15], c3.w, acc);
      if (acc < minv) { minv = acc; mink = code; }
    }
    unsigned long long best = ((unsigned long long)encf(t2 + minv) << 32)
        | (unsigned long long)((unsigned int)r * (unsigned int)NCODES + (unsigned int)mink);
#pragma unroll
    for (int s = 1; s < 64; s <<= 1) {
      unsigned long long o = __shfl_xor(best, s);
      best = (o < best) ? o : best;
    }
    if (l == 0) atomicMin(key, best);
  }
  __syncthreads();
  if (tid == 0) {
    __threadfence();
    if (atomicAdd(resctr, 1u) == (unsigned int)gridDim.x - 1u) {
      unsigned long long v = atomicMin(key, 0xFFFFFFFFFFFFFFFFull);
      out[0] = (int)(unsigned int)(v & 0xFFFFFFFFull);
    }
  }
}

extern "C" void kernel_launch(void* const* d_in, const int* in_sizes, int n_in,
                              void* d_out, int out_size, void* d_ws, size_t ws_size,
                              hipStream_t stream) {
  const float* x    = (const float*)d_in[0];
  const int*   mask = (const int*)d_in[1];
  const float* W    = (const float*)d_in[2];
  const float* cbk  = (const float*)d_in[3];
  int* out = (int*)d_out;

  char* ws = (char*)d_ws;                                   // total 1,810,432 B
  unsigned int*       chunksum  = (unsigned int*)(ws);              // 2048
  int*                chunkpref = (int*)(ws + 2048);                // 2048
  unsigned int*       prepctr   = (unsigned int*)(ws + 4096);       // 4
  unsigned int*       p1ctr     = (unsigned int*)(ws + 4100);       // 4
  unsigned int*       resctr    = (unsigned int*)(ws + 4104);       // 4
  unsigned int*       candcount = (unsigned int*)(ws + 4108);       // 4
  unsigned long long* key       = (unsigned long long*)(ws + 4112); // 8
  float*              pmax_c2   = (float*)(ws + 4128);              // 64
  unsigned int*       rowmin_u  = (unsigned int*)(ws + 8192);       // 64 KiB
  float*              t2arr     = (float*)(ws + 73728);             // 64 KiB
  int*                origrow   = (int*)(ws + 139264);              // 64 KiB
  float*              c2        = (float*)(ws + 204800);            // 32 KiB
  unsigned short*     cbf32     = (unsigned short*)(ws + 237568);   // 512 KiB
  int*                candlist  = (int*)(ws + 237568);              // aliases cbf32 (dead when written)
  unsigned short*     tbf32     = (unsigned short*)(ws + 761856);   // 1 MiB

  hipMemsetAsync(ws + 4096, 0, 16, stream);   // prepctr, p1ctr, resctr, candcount
  prep_kernel<<<80, 512, 0, stream>>>(mask, cbk, chunksum, chunkpref, c2, cbf32,
                                      pmax_c2, key, prepctr);
  project_kernel<<<512, 256, 0, stream>>>(x, mask, chunkpref, W, tbf32, t2arr, origrow);
  phase1_kernel<<<512, 1024, 0, stream>>>(tbf32, cbf32, t2arr, pmax_c2, rowmin_u,
                                          p1ctr, candcount, candlist);
  rescore_kernel<<<256, 256, 0, stream>>>(x, W, cbk, c2, origrow, candcount,
                                          candlist, key, resctr, out);
}

// Round 7
// 146.672 us; speedup vs baseline: 1.7577x; 1.7577x over previous
//
#include <hip/hip_runtime.h>
#include <hip/hip_bf16.h>

// RandomProjectionQuantizer — calibrated per-row MFMA screening, no atomic-RMW tail (R7).
//  x:(16,2048,320) f32, mask:(16,2048) i32 (exactly 16384 ones),
//  W:(16,320) f32, codebook:(8192,16) f32 -> scalar int32 label
//
//  Screening folds the FULL distance into the MFMA dot (R5/R6-verified):
//    A~ = [t(16), 1, 1, h1, h2, 0...]   (h1+h2 = bf16-split of ||t||^2)
//    C~ = [-2c(16), g1, g2, 1, 1, 0...] (g1+g2 = bf16-split of ||c||^2)
//  Row attribution calibrated at runtime via one identity-probe MFMA (R6-verified).
//  Gate = separate 1-block kernel with plain loads (kernel-boundary coherence,
//  R5-verified) — replaces R6's 147us single-block atomic-RMW tail.

#define NMASK   16384
#define D       320
#define CDIM    16
#define NCODES  8192
#define EPS_C   0.0117f      // 1.5 * 2^-7  (bf16 RNE dot-error coefficient)
#define EPS_ABS 0.02f

typedef __attribute__((ext_vector_type(8))) short short8;
typedef __attribute__((ext_vector_type(4))) float f32x4;

__device__ inline unsigned int encf(float f) {
  unsigned int u = __float_as_uint(f);
  return (u & 0x80000000u) ? ~u : (u | 0x80000000u);
}
__device__ inline float decf(unsigned int u) {
  unsigned int b = (u & 0x80000000u) ? (u & 0x7fffffffu) : ~u;
  return __uint_as_float(b);
}
__device__ inline unsigned short f2bf(float f) {   // RNE f32->bf16
  unsigned int u = __float_as_uint(f);
  unsigned int r = u + 0x7fffu + ((u >> 16) & 1u);
  return (unsigned short)(r >> 16);
}
__device__ inline float bf2f(unsigned short h) {
  return __uint_as_float(((unsigned int)h) << 16);
}

// shared projection chain: 4 lanes/row (chunk ch of 80), butterfly combine.
// Bit-identical between project and rescore (R5/R6-verified).
__device__ inline void proj_row(const float* __restrict__ x,
                                const float* __restrict__ W,
                                int row, int ch, float pd[16]) {
#pragma unroll
  for (int c = 0; c < 16; ++c) pd[c] = 0.f;
  const float4* xp = (const float4*)(x + (size_t)row * D + ch * 80);
#pragma unroll 4
  for (int j = 0; j < 20; ++j) {
    float4 xv = xp[j];
#pragma unroll
    for (int c = 0; c < 16; ++c) {
      const float4 wv = *(const float4*)(W + c * D + ch * 80 + j * 4);
      float acc = fmaf(xv.x, wv.x, pd[c]);
      acc = fmaf(xv.y, wv.y, acc);
      acc = fmaf(xv.z, wv.z, acc);
      pd[c] = fmaf(xv.w, wv.w, acc);
    }
  }
#pragma unroll
  for (int c = 0; c < 16; ++c) {
    pd[c] += __shfl_xor(pd[c], 1);
    pd[c] += __shfl_xor(pd[c], 2);
  }
}

// ---------------- Kernel 1: prep (80 blocks x 512) ---------------------------
__global__ __launch_bounds__(512) void prep_kernel(
    const int* __restrict__ mask, const float* __restrict__ cbk,
    unsigned int* __restrict__ chunksum, int* __restrict__ chunkpref,
    float* __restrict__ c2, unsigned short* __restrict__ cbf32,
    float* __restrict__ pmax_c2, unsigned int* __restrict__ rowmin_u,
    unsigned long long* __restrict__ key, unsigned int* __restrict__ prepctr) {
  __shared__ int lastf;
  int tid = threadIdx.x, bid = (int)blockIdx.x;
  if (bid < 64) {                                   // 64 blocks x 8 waves = 512 chunks
    int wv = tid >> 6, lane = tid & 63;
    int c = bid * 8 + wv;
    int m = mask[c * 64 + lane];
    unsigned long long bal = __ballot(m != 0);
    if (lane == 0) atomicExch(&chunksum[c], (unsigned int)__popcll(bal));
  } else {                                          // 16 blocks x 512 codes
    __shared__ float sm[512];
    int b = bid - 64;
    int k = b * 512 + tid;
    const float4* p = (const float4*)(cbk + (long)k * CDIM);
    float s = 0.f; unsigned short nb[16];
#pragma unroll
    for (int q = 0; q < 4; ++q) {
      float4 v = p[q];
      s = fmaf(v.x, v.x, s); s = fmaf(v.y, v.y, s);
      s = fmaf(v.z, v.z, s); s = fmaf(v.w, v.w, s);
      nb[q*4+0] = f2bf(-2.0f * v.x); nb[q*4+1] = f2bf(-2.0f * v.y);
      nb[q*4+2] = f2bf(-2.0f * v.z); nb[q*4+3] = f2bf(-2.0f * v.w);
    }
    c2[k] = s;
    unsigned short g1 = f2bf(s);
    unsigned short g2 = f2bf(s - bf2f(g1));
    uint4 pk0, pk1, pk2, pk3;
    pk0.x = (unsigned int)nb[0]  | ((unsigned int)nb[1]  << 16);
    pk0.y = (unsigned int)nb[2]  | ((unsigned int)nb[3]  << 16);
    pk0.z = (unsigned int)nb[4]  | ((unsigned int)nb[5]  << 16);
    pk0.w = (unsigned int)nb[6]  | ((unsigned int)nb[7]  << 16);
    pk1.x = (unsigned int)nb[8]  | ((unsigned int)nb[9]  << 16);
    pk1.y = (unsigned int)nb[10] | ((unsigned int)nb[11] << 16);
    pk1.z = (unsigned int)nb[12] | ((unsigned int)nb[13] << 16);
    pk1.w = (unsigned int)nb[14] | ((unsigned int)nb[15] << 16);
    pk2.x = (unsigned int)g1 | ((unsigned int)g2 << 16); // dims 16,17: g1,g2
    pk2.y = 0x3F803F80u;                                 // dims 18,19: 1,1
    pk2.z = 0u; pk2.w = 0u;
    pk3.x = 0u; pk3.y = 0u; pk3.z = 0u; pk3.w = 0u;
    uint4* dst = (uint4*)(cbf32 + (long)k * 32);
    dst[0] = pk0; dst[1] = pk1; dst[2] = pk2; dst[3] = pk3;
    rowmin_u[b * 1024 + tid]       = 0xFFFFFFFFu;   // init 16 x 1024 = 16384
    rowmin_u[b * 1024 + 512 + tid] = 0xFFFFFFFFu;
    if (b == 0 && tid == 0) key[0] = 0xFFFFFFFFFFFFFFFFull;
    sm[tid] = s; __syncthreads();
    for (int st = 256; st > 0; st >>= 1) {
      if (tid < st) sm[tid] = fmaxf(sm[tid], sm[tid + st]);
      __syncthreads();
    }
    if (tid == 0) pmax_c2[b] = sm[0];
  }
  __threadfence();
  __syncthreads();
  if (tid == 0) lastf = (atomicAdd(prepctr, 1u) == 79u) ? 1 : 0;
  __syncthreads();
  if (lastf) {                                      // last block: 512-chunk scan
    __shared__ int a[512], bb[512];
    a[tid] = (int)atomicAdd(&chunksum[tid], 0u);
    __syncthreads();
    int *src = a, *dst2 = bb;
    for (int off = 1; off < 512; off <<= 1) {
      dst2[tid] = src[tid] + (tid >= off ? src[tid - off] : 0);
      __syncthreads();
      int* t = src; src = dst2; dst2 = t;
    }
    chunkpref[tid] = (tid == 0) ? 0 : src[tid - 1];
  }
}

// ---------------- Kernel 2: project (512 blocks x 256) -----------------------
__global__ __launch_bounds__(256) void project_kernel(
    const float* __restrict__ x, const int* __restrict__ mask,
    const int* __restrict__ chunkpref, const float* __restrict__ W,
    unsigned short* __restrict__ tbf32, float* __restrict__ t2arr,
    int* __restrict__ origrow) {
  __shared__ unsigned long long mb;
  int tid = threadIdx.x, bid = (int)blockIdx.x;
  int base = bid * 64;
  if (tid < 64) {
    int m = mask[base + tid];
    unsigned long long bal = __ballot(m != 0);
    if (tid == 0) mb = bal;
  }
  __syncthreads();
  unsigned long long B0 = mb;
  int r = tid >> 2, ch = tid & 3;
  int row = base + r;
  int m = (int)((B0 >> r) & 1ull);
  if (!m) return;
  float pd[16];
  proj_row(x, W, row, ch, pd);
  if (ch == 0) {
    int rank = chunkpref[bid] + __popcll(B0 & ((1ull << r) - 1ull));
    float t2 = 0.f;
#pragma unroll
    for (int c = 0; c < 16; ++c) t2 = fmaf(pd[c], pd[c], t2);
    t2arr[rank] = t2;
    origrow[rank] = row;
    unsigned short tb[16];
#pragma unroll
    for (int c = 0; c < 16; ++c) tb[c] = f2bf(pd[c]);
    unsigned short h1 = f2bf(t2);
    unsigned short h2 = f2bf(t2 - bf2f(h1));
    uint4 pk0, pk1, pk2, pk3;
    pk0.x = (unsigned int)tb[0]  | ((unsigned int)tb[1]  << 16);
    pk0.y = (unsigned int)tb[2]  | ((unsigned int)tb[3]  << 16);
    pk0.z = (unsigned int)tb[4]  | ((unsigned int)tb[5]  << 16);
    pk0.w = (unsigned int)tb[6]  | ((unsigned int)tb[7]  << 16);
    pk1.x = (unsigned int)tb[8]  | ((unsigned int)tb[9]  << 16);
    pk1.y = (unsigned int)tb[10] | ((unsigned int)tb[11] << 16);
    pk1.z = (unsigned int)tb[12] | ((unsigned int)tb[13] << 16);
    pk1.w = (unsigned int)tb[14] | ((unsigned int)tb[15] << 16);
    pk2.x = 0x3F803F80u;                                 // dims 16,17: 1,1
    pk2.y = (unsigned int)h1 | ((unsigned int)h2 << 16); // dims 18,19: h1,h2
    pk2.z = 0u; pk2.w = 0u;
    pk3.x = 0u; pk3.y = 0u; pk3.z = 0u; pk3.w = 0u;
    uint4* dst = (uint4*)(tbf32 + (long)rank * 32);
    dst[0] = pk0; dst[1] = pk1; dst[2] = pk2; dst[3] = pk3;
  }
}

// ---------------- Kernel 3: calibrated per-row MFMA screening ----------------
// 2048 blocks x 256 (4 waves). Block = (strip of 32 ranks) x (4 of 16 segs);
// wave = one 512-code seg. Per-block LDS min combine, one global atomicMin
// per row per block. No ticket, no tail.
__global__ __launch_bounds__(256) void phase1_kernel(
    const unsigned short* __restrict__ tbf32,
    const unsigned short* __restrict__ cbf32,
    unsigned int* __restrict__ rowmin_u) {
  __shared__ unsigned int rml[4 * 33];              // per-wave padded rowmin
  int tid = threadIdx.x;
  int w = tid >> 6, l = tid & 63, lr = l & 15, g = l >> 4;
  int strip = (int)blockIdx.x >> 2;                 // 0..511
  int seg   = ((int)blockIdx.x & 3) * 4 + w;        // 0..15
  int row0 = strip * 32;

  for (int i = tid; i < 4 * 33; i += 256) rml[i] = 0xFFFFFFFFu;
  __syncthreads();

  const f32x4 zero = {0.f, 0.f, 0.f, 0.f};
  // --- calibration MFMA: learn sigma(lane, reg) = output row index (R6-verified)
  short8 calA = {0,0,0,0,0,0,0,0}, calB = {0,0,0,0,0,0,0,0};
  if (g == 0) {
    calA[0] = (short)f2bf((float)(lr + 1));
    calB[0] = (short)0x3F80;                        // bf16 1.0
  }
  f32x4 cal = __builtin_amdgcn_mfma_f32_16x16x32_bf16(calA, calB, zero, 0, 0, 0);
  int rid[4];
#pragma unroll
  for (int j = 0; j < 4; ++j) {
    int v = (int)(cal[j] + 0.5f) - 1;
    rid[j] = v < 0 ? 0 : (v > 15 ? 15 : v);
  }

  const short8 a0 = *(const short8*)(tbf32 + (long)(row0 + lr) * 32 + g * 8);
  const short8 a1 = *(const short8*)(tbf32 + (long)(row0 + 16 + lr) * 32 + g * 8);
  f32x4 rmin0 = {3.4e38f, 3.4e38f, 3.4e38f, 3.4e38f};
  f32x4 rmin1 = rmin0;
  int code0 = seg * 512;
#pragma unroll 2
  for (int t = 0; t < 32; ++t) {
    int code = code0 + t * 16 + lr;
    short8 b = *(const short8*)(cbf32 + (long)code * 32 + g * 8);
    f32x4 d0 = __builtin_amdgcn_mfma_f32_16x16x32_bf16(a0, b, zero, 0, 0, 0);
    f32x4 d1 = __builtin_amdgcn_mfma_f32_16x16x32_bf16(a1, b, zero, 0, 0, 0);
#pragma unroll
    for (int j = 0; j < 4; ++j) {
      rmin0[j] = fminf(rmin0[j], d0[j]);
      rmin1[j] = fminf(rmin1[j], d1[j]);
    }
  }
  unsigned int* mywave = &rml[w * 33];
#pragma unroll
  for (int j = 0; j < 4; ++j) {
    atomicMin(&mywave[rid[j]],      encf(rmin0[j]));
    atomicMin(&mywave[16 + rid[j]], encf(rmin1[j]));
  }
  __syncthreads();
  if (tid < 32) {                                   // combine 4 waves -> global
    unsigned int mn = 0xFFFFFFFFu;
#pragma unroll
    for (int ww = 0; ww < 4; ++ww) mn = min(mn, rml[ww * 33 + tid]);
    atomicMin(&rowmin_u[row0 + tid], mn);
  }
}

// ---------------- Kernel 4: gate (1 block x 1024, plain loads) ---------------
__global__ __launch_bounds__(1024) void gate_kernel(
    const unsigned int* __restrict__ rowmin_u, const float* __restrict__ t2arr,
    const float* __restrict__ pmax_c2,
    unsigned int* __restrict__ candcount, int* __restrict__ candlist) {
  __shared__ float sT[1024];
  int tid = threadIdx.x;
  float c2m = 0.f;
#pragma unroll
  for (int i = 0; i < 16; ++i) c2m = fmaxf(c2m, pmax_c2[i]);
  float Tl = 3.4e38f;
  for (int i = tid; i < NMASK; i += 1024) {
    float a = decf(rowmin_u[i]);
    float e = fmaf(EPS_C, sqrtf(t2arr[i] * c2m), EPS_ABS);
    Tl = fminf(Tl, a + e);                          // NaN -> ignored
  }
  sT[tid] = Tl; __syncthreads();
  for (int st = 512; st > 0; st >>= 1) {
    if (tid < st) sT[tid] = fminf(sT[tid], sT[tid + st]);
    __syncthreads();
  }
  float T = sT[0];
  for (int i = tid; i < NMASK; i += 1024) {
    float a = decf(rowmin_u[i]);
    float e = fmaf(EPS_C, sqrtf(t2arr[i] * c2m), EPS_ABS);
    if (!(a - e > T)) {                             // NaN-safe: NaN -> candidate
      unsigned int pos = atomicAdd(candcount, 1u);
      candlist[pos] = i;
    }
  }
}

// ---------------- Kernel 5: exact rescore of candidate rows + emit -----------
__global__ __launch_bounds__(256) void rescore_kernel(
    const float* __restrict__ x, const float* __restrict__ W,
    const float* __restrict__ cbk, const float* __restrict__ c2,
    const int* __restrict__ origrow, const unsigned int* __restrict__ candcount,
    const int* __restrict__ candlist, unsigned long long* __restrict__ key,
    unsigned int* __restrict__ resctr, int* __restrict__ out) {
  int tid = threadIdx.x, bid = (int)blockIdx.x;
  int l = tid & 63, ch = l & 3;
  int nc = (int)candcount[0];
  for (int idx = bid * 4 + (tid >> 6); idx < nc; idx += 1024) {
    int r = candlist[idx];
    int row = origrow[r];
    float pd[16];
    proj_row(x, W, row, ch, pd);                    // bit-identical to project
    float t2 = 0.f, tm[16];
#pragma unroll
    for (int c = 0; c < 16; ++c) t2 = fmaf(pd[c], pd[c], t2);
#pragma unroll
    for (int c = 0; c < 16; ++c) tm[c] = -2.0f * pd[c];
    float minv = 3.4e38f; int mink = 0;
    for (int j = 0; j < 128; ++j) {                 // 128 codes per lane
      int code = j * 64 + l;
      const float4* cp = (const float4*)(cbk + (long)code * CDIM);
      float4 c0 = cp[0], c1 = cp[1], c2v4 = cp[2], c3 = cp[3];
      float acc = fmaf(tm[0],  c0.x, c2[code]);
      acc = fmaf(tm[1],  c0.y, acc);   acc = fmaf(tm[2],  c0.z, acc);
      acc = fmaf(tm[3],  c0.w, acc);   acc = fmaf(tm[4],  c1.x, acc);
      acc = fmaf(tm[5],  c1.y, acc);   acc = fmaf(tm[6],  c1.z, acc);
      acc = fmaf(tm[7],  c1.w, acc);   acc = fmaf(tm[8],  c2v4.x, acc);
      acc = fmaf(tm[9],  c2v4.y, acc); acc = fmaf(tm[10], c2v4.z, acc);
      acc = fmaf(tm[11], c2v4.w, acc); acc = fmaf(tm[12], c3.x, acc);
      acc = fmaf(tm[13], c3.y, acc);   acc = fmaf(tm[14], c3.z, acc);
      acc = fmaf(tm[15], c3.w, acc);
      if (acc < minv) { minv = acc; mink = code; }
    }
    unsigned long long best = ((unsigned long long)encf(t2 + minv) << 32)
        | (unsigned long long)((unsigned int)r * (unsigned int)NCODES + (unsigned int)mink);
#pragma unroll
    for (int s = 1; s < 64; s <<= 1) {
      unsigned long long o = __shfl_xor(best, s);
      best = (o < best) ? o : best;
    }
    if (l == 0) atomicMin(key, best);
  }
  __syncthreads();
  if (tid == 0) {
    __threadfence();
    if (atomicAdd(resctr, 1u) == (unsigned int)gridDim.x - 1u) {
      unsigned long long v = atomicMin(key, 0xFFFFFFFFFFFFFFFFull);
      out[0] = (int)(unsigned int)(v & 0xFFFFFFFFull);
    }
  }
}

extern "C" void kernel_launch(void* const* d_in, const int* in_sizes, int n_in,
                              void* d_out, int out_size, void* d_ws, size_t ws_size,
                              hipStream_t stream) {
  const float* x    = (const float*)d_in[0];
  const int*   mask = (const int*)d_in[1];
  const float* W    = (const float*)d_in[2];
  const float* cbk  = (const float*)d_in[3];
  int* out = (int*)d_out;

  char* ws = (char*)d_ws;                                   // total 1,810,432 B
  unsigned int*       chunksum  = (unsigned int*)(ws);              // 2048
  int*                chunkpref = (int*)(ws + 2048);                // 2048
  unsigned int*       prepctr   = (unsigned int*)(ws + 4096);       // 4
  unsigned int*       resctr    = (unsigned int*)(ws + 4100);       // 4
  unsigned int*       candcount = (unsigned int*)(ws + 4108);       // 4
  unsigned long long* key       = (unsigned long long*)(ws + 4112); // 8
  float*              pmax_c2   = (float*)(ws + 4128);              // 64
  unsigned int*       rowmin_u  = (unsigned int*)(ws + 8192);       // 64 KiB
  float*              t2arr     = (float*)(ws + 73728);             // 64 KiB
  int*                origrow   = (int*)(ws + 139264);              // 64 KiB
  float*              c2        = (float*)(ws + 204800);            // 32 KiB
  unsigned short*     cbf32     = (unsigned short*)(ws + 237568);   // 512 KiB
  int*                candlist  = (int*)(ws + 237568);              // aliases cbf32 (dead by gate time)
  unsigned short*     tbf32     = (unsigned short*)(ws + 761856);   // 1 MiB

  hipMemsetAsync(ws + 4096, 0, 16, stream);   // prepctr, resctr, candcount
  prep_kernel<<<80, 512, 0, stream>>>(mask, cbk, chunksum, chunkpref, c2, cbf32,
                                      pmax_c2, rowmin_u, key, prepctr);
  project_kernel<<<512, 256, 0, stream>>>(x, mask, chunkpref, W, tbf32, t2arr, origrow);
  phase1_kernel<<<2048, 256, 0, stream>>>(tbf32, cbf32, rowmin_u);
  gate_kernel<<<1, 1024, 0, stream>>>(rowmin_u, t2arr, pmax_c2, candcount, candlist);
  rescore_kernel<<<256, 256, 0, stream>>>(x, W, cbk, c2, origrow, candcount,
                                          candlist, key, resctr, out);
}

// Round 8
// 130.743 us; speedup vs baseline: 1.9719x; 1.1218x over previous
//
#include <hip/hip_runtime.h>
#include <hip/hip_bf16.h>

// RandomProjectionQuantizer — MFMA screen + parallel exact rescore (R8).
//  x:(16,2048,320) f32, mask:(16,2048) i32 (exactly 16384 ones),
//  W:(16,320) f32, codebook:(8192,16) f32 -> scalar int32 label
//
//  scan    : 1 block — chunk prefix scan, rowmin/key/c2max init.
//  project : 1024 blocks, 8 lanes/row; fused codebook bf16 conversion (R5 fold
//            format), c2, c2max.
//  phase1  : R7-verbatim calibrated per-row MFMA screening.
//  gate    : 1 block — T = min_r(a_r+eps_r), candidate list, stored candcount.
//  rescore : block-per-candidate exact f32 argmin (codes split across 256
//            threads, unrolled), ticket-fused emit.

#define NMASK   16384
#define D       320
#define CDIM    16
#define NCODES  8192
#define EPS_C   0.0117f      // 1.5 * 2^-7  (bf16 RNE dot-error coefficient)
#define EPS_ABS 0.02f

typedef __attribute__((ext_vector_type(8))) short short8;
typedef __attribute__((ext_vector_type(4))) float f32x4;

__device__ inline unsigned int encf(float f) {
  unsigned int u = __float_as_uint(f);
  return (u & 0x80000000u) ? ~u : (u | 0x80000000u);
}
__device__ inline float decf(unsigned int u) {
  unsigned int b = (u & 0x80000000u) ? (u & 0x7fffffffu) : ~u;
  return __uint_as_float(b);
}
__device__ inline unsigned short f2bf(float f) {   // RNE f32->bf16
  unsigned int u = __float_as_uint(f);
  unsigned int r = u + 0x7fffu + ((u >> 16) & 1u);
  return (unsigned short)(r >> 16);
}
__device__ inline float bf2f(unsigned short h) {
  return __uint_as_float(((unsigned int)h) << 16);
}

// projection: 8 lanes/row (chunk ch of 40 floats), butterfly combine (xor 1,2,4).
__device__ inline void proj_row8(const float* __restrict__ x,
                                 const float* __restrict__ W,
                                 int row, int ch, float pd[16]) {
#pragma unroll
  for (int c = 0; c < 16; ++c) pd[c] = 0.f;
  const float4* xp = (const float4*)(x + (size_t)row * D + ch * 40);
#pragma unroll
  for (int j = 0; j < 10; ++j) {
    float4 xv = xp[j];
#pragma unroll
    for (int c = 0; c < 16; ++c) {
      const float4 wv = *(const float4*)(W + c * D + ch * 40 + j * 4);
      float acc = fmaf(xv.x, wv.x, pd[c]);
      acc = fmaf(xv.y, wv.y, acc);
      acc = fmaf(xv.z, wv.z, acc);
      pd[c] = fmaf(xv.w, wv.w, acc);
    }
  }
#pragma unroll
  for (int c = 0; c < 16; ++c) {
    pd[c] += __shfl_xor(pd[c], 1);
    pd[c] += __shfl_xor(pd[c], 2);
    pd[c] += __shfl_xor(pd[c], 4);
  }
}

// ---------------- Kernel 1: scan (1 block x 512) -----------------------------
__global__ __launch_bounds__(512) void scan_kernel(
    const int* __restrict__ mask, int* __restrict__ chunkpref,
    unsigned int* __restrict__ rowmin_u, unsigned long long* __restrict__ key,
    unsigned int* __restrict__ c2max_u) {
  __shared__ int a[512], b[512];
  int tid = threadIdx.x;
  const int4* mp = (const int4*)(mask + tid * 64);   // thread-per-chunk
  int cnt = 0;
#pragma unroll
  for (int i = 0; i < 16; ++i) {
    int4 v = mp[i];
    cnt += (v.x != 0) + (v.y != 0) + (v.z != 0) + (v.w != 0);
  }
  a[tid] = cnt; __syncthreads();
  int *src = a, *dst = b;
  for (int off = 1; off < 512; off <<= 1) {          // Hillis-Steele inclusive
    dst[tid] = src[tid] + (tid >= off ? src[tid - off] : 0);
    __syncthreads();
    int* t = src; src = dst; dst = t;
  }
  chunkpref[tid] = (tid == 0) ? 0 : src[tid - 1];    // exclusive
  for (int i = tid; i < NMASK; i += 512) rowmin_u[i] = 0xFFFFFFFFu;
  if (tid == 0) { key[0] = 0xFFFFFFFFFFFFFFFFull; c2max_u[0] = 0u; }
}

// ---------------- Kernel 2: project (1024 blocks x 256) ----------------------
// 32 rows/block, 8 lanes/row; blocks <512 also convert 16 codebook rows each.
__global__ __launch_bounds__(256) void project_kernel(
    const float* __restrict__ x, const int* __restrict__ mask,
    const int* __restrict__ chunkpref, const float* __restrict__ W,
    const float* __restrict__ cbk, float* __restrict__ c2,
    unsigned short* __restrict__ cbf32, unsigned short* __restrict__ tbf32,
    float* __restrict__ t2arr, int* __restrict__ origrow,
    unsigned int* __restrict__ c2max_u) {
  __shared__ unsigned long long mb;
  int tid = threadIdx.x, bid = (int)blockIdx.x;
  int chunk = bid >> 1, half = bid & 1;
  if (tid < 64) {
    int m = mask[chunk * 64 + tid];
    unsigned long long bal = __ballot(m != 0);
    if (tid == 0) mb = bal;
  }
  __syncthreads();
  if (bid < 512 && tid < 16) {                       // fused codes job (R5 fold)
    int k = bid * 16 + tid;
    const float4* p = (const float4*)(cbk + (long)k * CDIM);
    float s = 0.f; unsigned short nb[16];
#pragma unroll
    for (int q = 0; q < 4; ++q) {
      float4 v = p[q];
      s = fmaf(v.x, v.x, s); s = fmaf(v.y, v.y, s);
      s = fmaf(v.z, v.z, s); s = fmaf(v.w, v.w, s);
      nb[q*4+0] = f2bf(-2.0f * v.x); nb[q*4+1] = f2bf(-2.0f * v.y);
      nb[q*4+2] = f2bf(-2.0f * v.z); nb[q*4+3] = f2bf(-2.0f * v.w);
    }
    c2[k] = s;
    atomicMax(c2max_u, __float_as_uint(s));          // s >= 0: bits monotone
    unsigned short g1 = f2bf(s);
    unsigned short g2 = f2bf(s - bf2f(g1));
    uint4 pk0, pk1, pk2, pk3;
    pk0.x = (unsigned int)nb[0]  | ((unsigned int)nb[1]  << 16);
    pk0.y = (unsigned int)nb[2]  | ((unsigned int)nb[3]  << 16);
    pk0.z = (unsigned int)nb[4]  | ((unsigned int)nb[5]  << 16);
    pk0.w = (unsigned int)nb[6]  | ((unsigned int)nb[7]  << 16);
    pk1.x = (unsigned int)nb[8]  | ((unsigned int)nb[9]  << 16);
    pk1.y = (unsigned int)nb[10] | ((unsigned int)nb[11] << 16);
    pk1.z = (unsigned int)nb[12] | ((unsigned int)nb[13] << 16);
    pk1.w = (unsigned int)nb[14] | ((unsigned int)nb[15] << 16);
    pk2.x = (unsigned int)g1 | ((unsigned int)g2 << 16); // dims 16,17: g1,g2
    pk2.y = 0x3F803F80u;                                 // dims 18,19: 1,1
    pk2.z = 0u; pk2.w = 0u;
    pk3.x = 0u; pk3.y = 0u; pk3.z = 0u; pk3.w = 0u;
    uint4* dst = (uint4*)(cbf32 + (long)k * 32);
    dst[0] = pk0; dst[1] = pk1; dst[2] = pk2; dst[3] = pk3;
  }
  unsigned long long B0 = mb;
  int r = tid >> 3, ch = tid & 7;
  int p = half * 32 + r;                             // bit position in chunk
  int row = chunk * 64 + p;
  if (!((B0 >> p) & 1ull)) return;
  float pd[16];
  proj_row8(x, W, row, ch, pd);
  if (ch == 0) {
    int rank = chunkpref[chunk] + __popcll(B0 & ((1ull << p) - 1ull));
    float t2 = 0.f;
#pragma unroll
    for (int c = 0; c < 16; ++c) t2 = fmaf(pd[c], pd[c], t2);
    t2arr[rank] = t2;
    origrow[rank] = row;
    unsigned short tb[16];
#pragma unroll
    for (int c = 0; c < 16; ++c) tb[c] = f2bf(pd[c]);
    unsigned short h1 = f2bf(t2);
    unsigned short h2 = f2bf(t2 - bf2f(h1));
    uint4 pk0, pk1, pk2, pk3;
    pk0.x = (unsigned int)tb[0]  | ((unsigned int)tb[1]  << 16);
    pk0.y = (unsigned int)tb[2]  | ((unsigned int)tb[3]  << 16);
    pk0.z = (unsigned int)tb[4]  | ((unsigned int)tb[5]  << 16);
    pk0.w = (unsigned int)tb[6]  | ((unsigned int)tb[7]  << 16);
    pk1.x = (unsigned int)tb[8]  | ((unsigned int)tb[9]  << 16);
    pk1.y = (unsigned int)tb[10] | ((unsigned int)tb[11] << 16);
    pk1.z = (unsigned int)tb[12] | ((unsigned int)tb[13] << 16);
    pk1.w = (unsigned int)tb[14] | ((unsigned int)tb[15] << 16);
    pk2.x = 0x3F803F80u;                                 // dims 16,17: 1,1
    pk2.y = (unsigned int)h1 | ((unsigned int)h2 << 16); // dims 18,19: h1,h2
    pk2.z = 0u; pk2.w = 0u;
    pk3.x = 0u; pk3.y = 0u; pk3.z = 0u; pk3.w = 0u;
    uint4* dst = (uint4*)(tbf32 + (long)rank * 32);
    dst[0] = pk0; dst[1] = pk1; dst[2] = pk2; dst[3] = pk3;
  }
}

// ---------------- Kernel 3: calibrated per-row MFMA screening (R7-verbatim) --
__global__ __launch_bounds__(256) void phase1_kernel(
    const unsigned short* __restrict__ tbf32,
    const unsigned short* __restrict__ cbf32,
    unsigned int* __restrict__ rowmin_u) {
  __shared__ unsigned int rml[4 * 33];
  int tid = threadIdx.x;
  int w = tid >> 6, l = tid & 63, lr = l & 15, g = l >> 4;
  int strip = (int)blockIdx.x >> 2;                 // 0..511
  int seg   = ((int)blockIdx.x & 3) * 4 + w;        // 0..15
  int row0 = strip * 32;

  for (int i = tid; i < 4 * 33; i += 256) rml[i] = 0xFFFFFFFFu;
  __syncthreads();

  const f32x4 zero = {0.f, 0.f, 0.f, 0.f};
  short8 calA = {0,0,0,0,0,0,0,0}, calB = {0,0,0,0,0,0,0,0};
  if (g == 0) {
    calA[0] = (short)f2bf((float)(lr + 1));
    calB[0] = (short)0x3F80;                        // bf16 1.0
  }
  f32x4 cal = __builtin_amdgcn_mfma_f32_16x16x32_bf16(calA, calB, zero, 0, 0, 0);
  int rid[4];
#pragma unroll
  for (int j = 0; j < 4; ++j) {
    int v = (int)(cal[j] + 0.5f) - 1;
    rid[j] = v < 0 ? 0 : (v > 15 ? 15 : v);
  }

  const short8 a0 = *(const short8*)(tbf32 + (long)(row0 + lr) * 32 + g * 8);
  const short8 a1 = *(const short8*)(tbf32 + (long)(row0 + 16 + lr) * 32 + g * 8);
  f32x4 rmin0 = {3.4e38f, 3.4e38f, 3.4e38f, 3.4e38f};
  f32x4 rmin1 = rmin0;
  int code0 = seg * 512;
#pragma unroll 2
  for (int t = 0; t < 32; ++t) {
    int code = code0 + t * 16 + lr;
    short8 b = *(const short8*)(cbf32 + (long)code * 32 + g * 8);
    f32x4 d0 = __builtin_amdgcn_mfma_f32_16x16x32_bf16(a0, b, zero, 0, 0, 0);
    f32x4 d1 = __builtin_amdgcn_mfma_f32_16x16x32_bf16(a1, b, zero, 0, 0, 0);
#pragma unroll
    for (int j = 0; j < 4; ++j) {
      rmin0[j] = fminf(rmin0[j], d0[j]);
      rmin1[j] = fminf(rmin1[j], d1[j]);
    }
  }
  unsigned int* mywave = &rml[w * 33];
#pragma unroll
  for (int j = 0; j < 4; ++j) {
    atomicMin(&mywave[rid[j]],      encf(rmin0[j]));
    atomicMin(&mywave[16 + rid[j]], encf(rmin1[j]));
  }
  __syncthreads();
  if (tid < 32) {
    unsigned int mn = 0xFFFFFFFFu;
#pragma unroll
    for (int ww = 0; ww < 4; ++ww) mn = min(mn, rml[ww * 33 + tid]);
    atomicMin(&rowmin_u[row0 + tid], mn);
  }
}

// ---------------- Kernel 4: gate (1 block x 1024) ----------------------------
__global__ __launch_bounds__(1024) void gate_kernel(
    const unsigned int* __restrict__ rowmin_u, const float* __restrict__ t2arr,
    const unsigned int* __restrict__ c2max_u,
    unsigned int* __restrict__ candcount, int* __restrict__ candlist) {
  __shared__ float sT[1024];
  __shared__ unsigned int cnt;
  int tid = threadIdx.x;
  float c2m = __uint_as_float(c2max_u[0]);
  float Tl = 3.4e38f;
  for (int i = tid; i < NMASK; i += 1024) {
    float a = decf(rowmin_u[i]);
    float e = fmaf(EPS_C, sqrtf(t2arr[i] * c2m), EPS_ABS);
    Tl = fminf(Tl, a + e);                          // NaN -> ignored
  }
  sT[tid] = Tl;
  if (tid == 0) cnt = 0u;
  __syncthreads();
  for (int st = 512; st > 0; st >>= 1) {
    if (tid < st) sT[tid] = fminf(sT[tid], sT[tid + st]);
    __syncthreads();
  }
  float T = sT[0];
  for (int i = tid; i < NMASK; i += 1024) {
    float a = decf(rowmin_u[i]);
    float e = fmaf(EPS_C, sqrtf(t2arr[i] * c2m), EPS_ABS);
    if (!(a - e > T)) {                             // NaN-safe: NaN -> candidate
      unsigned int pos = atomicAdd(&cnt, 1u);
      candlist[pos] = i;
    }
  }
  __syncthreads();
  if (tid == 0) candcount[0] = cnt;                 // plain store, no init needed
}

// ---------------- Kernel 5: exact rescore, block-per-candidate + emit --------
__global__ __launch_bounds__(256) void rescore_kernel(
    const float* __restrict__ x, const float* __restrict__ W,
    const float* __restrict__ cbk, const float* __restrict__ c2,
    const int* __restrict__ origrow, const unsigned int* __restrict__ candcount,
    const int* __restrict__ candlist, unsigned long long* __restrict__ key,
    unsigned int* __restrict__ resctr, int* __restrict__ out) {
  __shared__ unsigned long long red[256];
  int tid = threadIdx.x, bid = (int)blockIdx.x;
  int nc = (int)candcount[0];
  for (int ci = bid; ci < nc; ci += (int)gridDim.x) {
    int r = candlist[ci];
    int row = origrow[r];
    int l = tid & 63;
    float pd[16];
    proj_row8(x, W, row, l & 7, pd);                // all lanes get full t
    float t2 = 0.f, tm[16];
#pragma unroll
    for (int c = 0; c < 16; ++c) t2 = fmaf(pd[c], pd[c], t2);
#pragma unroll
    for (int c = 0; c < 16; ++c) tm[c] = -2.0f * pd[c];
    float minv = 3.4e38f; int mink = 0;
#pragma unroll 4
    for (int j = 0; j < 32; ++j) {                  // 32 codes/thread, 4 in flight
      int code = j * 256 + tid;
      const float4* cp = (const float4*)(cbk + (long)code * CDIM);
      float4 c0 = cp[0], c1 = cp[1], c2v4 = cp[2], c3 = cp[3];
      float acc = fmaf(tm[0],  c0.x, c2[code]);
      acc = fmaf(tm[1],  c0.y, acc);   acc = fmaf(tm[2],  c0.z, acc);
      acc = fmaf(tm[3],  c0.w, acc);   acc = fmaf(tm[4],  c1.x, acc);
      acc = fmaf(tm[5],  c1.y, acc);   acc = fmaf(tm[6],  c1.z, acc);
      acc = fmaf(tm[7],  c1.w, acc);   acc = fmaf(tm[8],  c2v4.x, acc);
      acc = fmaf(tm[9],  c2v4.y, acc); acc = fmaf(tm[10], c2v4.z, acc);
      acc = fmaf(tm[11], c2v4.w, acc); acc = fmaf(tm[12], c3.x, acc);
      acc = fmaf(tm[13], c3.y, acc);   acc = fmaf(tm[14], c3.z, acc);
      acc = fmaf(tm[15], c3.w, acc);
      if (acc < minv) { minv = acc; mink = code; }
    }
    red[tid] = ((unsigned long long)encf(t2 + minv) << 32)
        | (unsigned long long)((unsigned int)r * (unsigned int)NCODES + (unsigned int)mink);
    __syncthreads();
    for (int s = 128; s > 0; s >>= 1) {
      if (tid < s) { if (red[tid + s] < red[tid]) red[tid] = red[tid + s]; }
      __syncthreads();
    }
    if (tid == 0) atomicMin(key, red[0]);
    __syncthreads();                                // LDS reuse across ci
  }
  if (tid == 0) {
    __threadfence();
    if (atomicAdd(resctr, 1u) == (unsigned int)gridDim.x - 1u) {
      unsigned long long v = atomicMin(key, 0xFFFFFFFFFFFFFFFFull);
      out[0] = (int)(unsigned int)(v & 0xFFFFFFFFull);
    }
  }
}

extern "C" void kernel_launch(void* const* d_in, const int* in_sizes, int n_in,
                              void* d_out, int out_size, void* d_ws, size_t ws_size,
                              hipStream_t stream) {
  const float* x    = (const float*)d_in[0];
  const int*   mask = (const int*)d_in[1];
  const float* W    = (const float*)d_in[2];
  const float* cbk  = (const float*)d_in[3];
  int* out = (int*)d_out;

  char* ws = (char*)d_ws;                                   // total 1,810,432 B
  int*                chunkpref = (int*)(ws + 2048);                // 2048
  unsigned int*       resctr    = (unsigned int*)(ws + 4100);       // 4
  unsigned int*       candcount = (unsigned int*)(ws + 4108);       // 4
  unsigned long long* key       = (unsigned long long*)(ws + 4112); // 8
  unsigned int*       c2max_u   = (unsigned int*)(ws + 4128);       // 4
  unsigned int*       rowmin_u  = (unsigned int*)(ws + 8192);       // 64 KiB
  float*              t2arr     = (float*)(ws + 73728);             // 64 KiB
  int*                origrow   = (int*)(ws + 139264);              // 64 KiB
  float*              c2        = (float*)(ws + 204800);            // 32 KiB
  unsigned short*     cbf32     = (unsigned short*)(ws + 237568);   // 512 KiB
  int*                candlist  = (int*)(ws + 237568);              // aliases cbf32 (dead by gate time)
  unsigned short*     tbf32     = (unsigned short*)(ws + 761856);   // 1 MiB

  hipMemsetAsync(ws + 4096, 0, 16, stream);                 // resctr (+spare)
  scan_kernel<<<1, 512, 0, stream>>>(mask, chunkpref, rowmin_u, key, c2max_u);
  project_kernel<<<1024, 256, 0, stream>>>(x, mask, chunkpref, W, cbk, c2, cbf32,
                                           tbf32, t2arr, origrow, c2max_u);
  phase1_kernel<<<2048, 256, 0, stream>>>(tbf32, cbf32, rowmin_u);
  gate_kernel<<<1, 1024, 0, stream>>>(rowmin_u, t2arr, c2max_u, candcount, candlist);
  rescore_kernel<<<64, 256, 0, stream>>>(x, W, cbk, c2, origrow, candcount,
                                         candlist, key, resctr, out);
}

// Round 9
// 119.697 us; speedup vs baseline: 2.1539x; 1.0923x over previous
//
#include <hip/hip_runtime.h>
#include <hip/hip_bf16.h>

// RandomProjectionQuantizer — MFMA screen + block-split exact rescore (R9).
//  x:(16,2048,320) f32, mask:(16,2048) i32 (exactly 16384 ones),
//  W:(16,320) f32, codebook:(8192,16) f32 -> scalar int32 label
//
//  scan    : 1 block — chunk prefix scan, rowmin/key/c2max init.        (R8-verbatim)
//  project : 1024 blocks, 8 lanes/row + fused codebook fold conversion. (R8-verbatim)
//  phase1  : calibrated per-row MFMA screening.                         (R7-verbatim)
//  gate    : 1 block — T = min_r(a_r+eps_r), candidate list.            (R8-verbatim)
//  rescore : work unit = (candidate, 1024-code octant); 4 codes/thread,
//            no unroll-spill (R8's VGPR=256 + 452KB scratch writes fixed).

#define NMASK   16384
#define D       320
#define CDIM    16
#define NCODES  8192
#define EPS_C   0.0117f      // 1.5 * 2^-7  (bf16 RNE dot-error coefficient)
#define EPS_ABS 0.02f

typedef __attribute__((ext_vector_type(8))) short short8;
typedef __attribute__((ext_vector_type(4))) float f32x4;

__device__ inline unsigned int encf(float f) {
  unsigned int u = __float_as_uint(f);
  return (u & 0x80000000u) ? ~u : (u | 0x80000000u);
}
__device__ inline float decf(unsigned int u) {
  unsigned int b = (u & 0x80000000u) ? (u & 0x7fffffffu) : ~u;
  return __uint_as_float(b);
}
__device__ inline unsigned short f2bf(float f) {   // RNE f32->bf16
  unsigned int u = __float_as_uint(f);
  unsigned int r = u + 0x7fffu + ((u >> 16) & 1u);
  return (unsigned short)(r >> 16);
}
__device__ inline float bf2f(unsigned short h) {
  return __uint_as_float(((unsigned int)h) << 16);
}

// projection: 8 lanes/row (chunk ch of 40 floats), butterfly combine (xor 1,2,4).
// Bit-identical between project and rescore (R8-verified).
__device__ inline void proj_row8(const float* __restrict__ x,
                                 const float* __restrict__ W,
                                 int row, int ch, float pd[16]) {
#pragma unroll
  for (int c = 0; c < 16; ++c) pd[c] = 0.f;
  const float4* xp = (const float4*)(x + (size_t)row * D + ch * 40);
#pragma unroll
  for (int j = 0; j < 10; ++j) {
    float4 xv = xp[j];
#pragma unroll
    for (int c = 0; c < 16; ++c) {
      const float4 wv = *(const float4*)(W + c * D + ch * 40 + j * 4);
      float acc = fmaf(xv.x, wv.x, pd[c]);
      acc = fmaf(xv.y, wv.y, acc);
      acc = fmaf(xv.z, wv.z, acc);
      pd[c] = fmaf(xv.w, wv.w, acc);
    }
  }
#pragma unroll
  for (int c = 0; c < 16; ++c) {
    pd[c] += __shfl_xor(pd[c], 1);
    pd[c] += __shfl_xor(pd[c], 2);
    pd[c] += __shfl_xor(pd[c], 4);
  }
}

// ---------------- Kernel 1: scan (1 block x 512) -----------------------------
__global__ __launch_bounds__(512) void scan_kernel(
    const int* __restrict__ mask, int* __restrict__ chunkpref,
    unsigned int* __restrict__ rowmin_u, unsigned long long* __restrict__ key,
    unsigned int* __restrict__ c2max_u) {
  __shared__ int a[512], b[512];
  int tid = threadIdx.x;
  const int4* mp = (const int4*)(mask + tid * 64);   // thread-per-chunk
  int cnt = 0;
#pragma unroll
  for (int i = 0; i < 16; ++i) {
    int4 v = mp[i];
    cnt += (v.x != 0) + (v.y != 0) + (v.z != 0) + (v.w != 0);
  }
  a[tid] = cnt; __syncthreads();
  int *src = a, *dst = b;
  for (int off = 1; off < 512; off <<= 1) {          // Hillis-Steele inclusive
    dst[tid] = src[tid] + (tid >= off ? src[tid - off] : 0);
    __syncthreads();
    int* t = src; src = dst; dst = t;
  }
  chunkpref[tid] = (tid == 0) ? 0 : src[tid - 1];    // exclusive
  for (int i = tid; i < NMASK; i += 512) rowmin_u[i] = 0xFFFFFFFFu;
  if (tid == 0) { key[0] = 0xFFFFFFFFFFFFFFFFull; c2max_u[0] = 0u; }
}

// ---------------- Kernel 2: project (1024 blocks x 256) ----------------------
// 32 rows/block, 8 lanes/row; blocks <512 also convert 16 codebook rows each.
__global__ __launch_bounds__(256) void project_kernel(
    const float* __restrict__ x, const int* __restrict__ mask,
    const int* __restrict__ chunkpref, const float* __restrict__ W,
    const float* __restrict__ cbk, float* __restrict__ c2,
    unsigned short* __restrict__ cbf32, unsigned short* __restrict__ tbf32,
    float* __restrict__ t2arr, int* __restrict__ origrow,
    unsigned int* __restrict__ c2max_u) {
  __shared__ unsigned long long mb;
  int tid = threadIdx.x, bid = (int)blockIdx.x;
  int chunk = bid >> 1, half = bid & 1;
  if (tid < 64) {
    int m = mask[chunk * 64 + tid];
    unsigned long long bal = __ballot(m != 0);
    if (tid == 0) mb = bal;
  }
  __syncthreads();
  if (bid < 512 && tid < 16) {                       // fused codes job (R5 fold)
    int k = bid * 16 + tid;
    const float4* p = (const float4*)(cbk + (long)k * CDIM);
    float s = 0.f; unsigned short nb[16];
#pragma unroll
    for (int q = 0; q < 4; ++q) {
      float4 v = p[q];
      s = fmaf(v.x, v.x, s); s = fmaf(v.y, v.y, s);
      s = fmaf(v.z, v.z, s); s = fmaf(v.w, v.w, s);
      nb[q*4+0] = f2bf(-2.0f * v.x); nb[q*4+1] = f2bf(-2.0f * v.y);
      nb[q*4+2] = f2bf(-2.0f * v.z); nb[q*4+3] = f2bf(-2.0f * v.w);
    }
    c2[k] = s;
    atomicMax(c2max_u, __float_as_uint(s));          // s >= 0: bits monotone
    unsigned short g1 = f2bf(s);
    unsigned short g2 = f2bf(s - bf2f(g1));
    uint4 pk0, pk1, pk2, pk3;
    pk0.x = (unsigned int)nb[0]  | ((unsigned int)nb[1]  << 16);
    pk0.y = (unsigned int)nb[2]  | ((unsigned int)nb[3]  << 16);
    pk0.z = (unsigned int)nb[4]  | ((unsigned int)nb[5]  << 16);
    pk0.w = (unsigned int)nb[6]  | ((unsigned int)nb[7]  << 16);
    pk1.x = (unsigned int)nb[8]  | ((unsigned int)nb[9]  << 16);
    pk1.y = (unsigned int)nb[10] | ((unsigned int)nb[11] << 16);
    pk1.z = (unsigned int)nb[12] | ((unsigned int)nb[13] << 16);
    pk1.w = (unsigned int)nb[14] | ((unsigned int)nb[15] << 16);
    pk2.x = (unsigned int)g1 | ((unsigned int)g2 << 16); // dims 16,17: g1,g2
    pk2.y = 0x3F803F80u;                                 // dims 18,19: 1,1
    pk2.z = 0u; pk2.w = 0u;
    pk3.x = 0u; pk3.y = 0u; pk3.z = 0u; pk3.w = 0u;
    uint4* dst = (uint4*)(cbf32 + (long)k * 32);
    dst[0] = pk0; dst[1] = pk1; dst[2] = pk2; dst[3] = pk3;
  }
  unsigned long long B0 = mb;
  int r = tid >> 3, ch = tid & 7;
  int p = half * 32 + r;                             // bit position in chunk
  int row = chunk * 64 + p;
  if (!((B0 >> p) & 1ull)) return;
  float pd[16];
  proj_row8(x, W, row, ch, pd);
  if (ch == 0) {
    int rank = chunkpref[chunk] + __popcll(B0 & ((1ull << p) - 1ull));
    float t2 = 0.f;
#pragma unroll
    for (int c = 0; c < 16; ++c) t2 = fmaf(pd[c], pd[c], t2);
    t2arr[rank] = t2;
    origrow[rank] = row;
    unsigned short tb[16];
#pragma unroll
    for (int c = 0; c < 16; ++c) tb[c] = f2bf(pd[c]);
    unsigned short h1 = f2bf(t2);
    unsigned short h2 = f2bf(t2 - bf2f(h1));
    uint4 pk0, pk1, pk2, pk3;
    pk0.x = (unsigned int)tb[0]  | ((unsigned int)tb[1]  << 16);
    pk0.y = (unsigned int)tb[2]  | ((unsigned int)tb[3]  << 16);
    pk0.z = (unsigned int)tb[4]  | ((unsigned int)tb[5]  << 16);
    pk0.w = (unsigned int)tb[6]  | ((unsigned int)tb[7]  << 16);
    pk1.x = (unsigned int)tb[8]  | ((unsigned int)tb[9]  << 16);
    pk1.y = (unsigned int)tb[10] | ((unsigned int)tb[11] << 16);
    pk1.z = (unsigned int)tb[12] | ((unsigned int)tb[13] << 16);
    pk1.w = (unsigned int)tb[14] | ((unsigned int)tb[15] << 16);
    pk2.x = 0x3F803F80u;                                 // dims 16,17: 1,1
    pk2.y = (unsigned int)h1 | ((unsigned int)h2 << 16); // dims 18,19: h1,h2
    pk2.z = 0u; pk2.w = 0u;
    pk3.x = 0u; pk3.y = 0u; pk3.z = 0u; pk3.w = 0u;
    uint4* dst = (uint4*)(tbf32 + (long)rank * 32);
    dst[0] = pk0; dst[1] = pk1; dst[2] = pk2; dst[3] = pk3;
  }
}

// ---------------- Kernel 3: calibrated per-row MFMA screening (R7-verbatim) --
__global__ __launch_bounds__(256) void phase1_kernel(
    const unsigned short* __restrict__ tbf32,
    const unsigned short* __restrict__ cbf32,
    unsigned int* __restrict__ rowmin_u) {
  __shared__ unsigned int rml[4 * 33];
  int tid = threadIdx.x;
  int w = tid >> 6, l = tid & 63, lr = l & 15, g = l >> 4;
  int strip = (int)blockIdx.x >> 2;                 // 0..511
  int seg   = ((int)blockIdx.x & 3) * 4 + w;        // 0..15
  int row0 = strip * 32;

  for (int i = tid; i < 4 * 33; i += 256) rml[i] = 0xFFFFFFFFu;
  __syncthreads();

  const f32x4 zero = {0.f, 0.f, 0.f, 0.f};
  short8 calA = {0,0,0,0,0,0,0,0}, calB = {0,0,0,0,0,0,0,0};
  if (g == 0) {
    calA[0] = (short)f2bf((float)(lr + 1));
    calB[0] = (short)0x3F80;                        // bf16 1.0
  }
  f32x4 cal = __builtin_amdgcn_mfma_f32_16x16x32_bf16(calA, calB, zero, 0, 0, 0);
  int rid[4];
#pragma unroll
  for (int j = 0; j < 4; ++j) {
    int v = (int)(cal[j] + 0.5f) - 1;
    rid[j] = v < 0 ? 0 : (v > 15 ? 15 : v);
  }

  const short8 a0 = *(const short8*)(tbf32 + (long)(row0 + lr) * 32 + g * 8);
  const short8 a1 = *(const short8*)(tbf32 + (long)(row0 + 16 + lr) * 32 + g * 8);
  f32x4 rmin0 = {3.4e38f, 3.4e38f, 3.4e38f, 3.4e38f};
  f32x4 rmin1 = rmin0;
  int code0 = seg * 512;
#pragma unroll 2
  for (int t = 0; t < 32; ++t) {
    int code = code0 + t * 16 + lr;
    short8 b = *(const short8*)(cbf32 + (long)code * 32 + g * 8);
    f32x4 d0 = __builtin_amdgcn_mfma_f32_16x16x32_bf16(a0, b, zero, 0, 0, 0);
    f32x4 d1 = __builtin_amdgcn_mfma_f32_16x16x32_bf16(a1, b, zero, 0, 0, 0);
#pragma unroll
    for (int j = 0; j < 4; ++j) {
      rmin0[j] = fminf(rmin0[j], d0[j]);
      rmin1[j] = fminf(rmin1[j], d1[j]);
    }
  }
  unsigned int* mywave = &rml[w * 33];
#pragma unroll
  for (int j = 0; j < 4; ++j) {
    atomicMin(&mywave[rid[j]],      encf(rmin0[j]));
    atomicMin(&mywave[16 + rid[j]], encf(rmin1[j]));
  }
  __syncthreads();
  if (tid < 32) {
    unsigned int mn = 0xFFFFFFFFu;
#pragma unroll
    for (int ww = 0; ww < 4; ++ww) mn = min(mn, rml[ww * 33 + tid]);
    atomicMin(&rowmin_u[row0 + tid], mn);
  }
}

// ---------------- Kernel 4: gate (1 block x 1024) ----------------------------
__global__ __launch_bounds__(1024) void gate_kernel(
    const unsigned int* __restrict__ rowmin_u, const float* __restrict__ t2arr,
    const unsigned int* __restrict__ c2max_u,
    unsigned int* __restrict__ candcount, int* __restrict__ candlist) {
  __shared__ float sT[1024];
  __shared__ unsigned int cnt;
  int tid = threadIdx.x;
  float c2m = __uint_as_float(c2max_u[0]);
  float Tl = 3.4e38f;
  for (int i = tid; i < NMASK; i += 1024) {
    float a = decf(rowmin_u[i]);
    float e = fmaf(EPS_C, sqrtf(t2arr[i] * c2m), EPS_ABS);
    Tl = fminf(Tl, a + e);                          // NaN -> ignored
  }
  sT[tid] = Tl;
  if (tid == 0) cnt = 0u;
  __syncthreads();
  for (int st = 512; st > 0; st >>= 1) {
    if (tid < st) sT[tid] = fminf(sT[tid], sT[tid + st]);
    __syncthreads();
  }
  float T = sT[0];
  for (int i = tid; i < NMASK; i += 1024) {
    float a = decf(rowmin_u[i]);
    float e = fmaf(EPS_C, sqrtf(t2arr[i] * c2m), EPS_ABS);
    if (!(a - e > T)) {                             // NaN-safe: NaN -> candidate
      unsigned int pos = atomicAdd(&cnt, 1u);
      candlist[pos] = i;
    }
  }
  __syncthreads();
  if (tid == 0) candcount[0] = cnt;                 // plain store, no init needed
}

// ---------------- Kernel 5: rescore, block = (candidate, code-octant) --------
// Each block: re-derive t exactly (proj_row8, bit-identical), scan 1024 codes
// with 4 codes/thread (20 loads in flight, ~100 VGPR, no spill), LDS reduce,
// u64 atomicMin merge; ticket-fused emit.
__global__ __launch_bounds__(256) void rescore_kernel(
    const float* __restrict__ x, const float* __restrict__ W,
    const float* __restrict__ cbk, const float* __restrict__ c2,
    const int* __restrict__ origrow, const unsigned int* __restrict__ candcount,
    const int* __restrict__ candlist, unsigned long long* __restrict__ key,
    unsigned int* __restrict__ resctr, int* __restrict__ out) {
  __shared__ unsigned long long red[256];
  int tid = threadIdx.x, bid = (int)blockIdx.x;
  int l = tid & 63;
  int nwork = (int)candcount[0] * 8;                // 8 octants x 1024 codes
  for (int wk = bid; wk < nwork; wk += (int)gridDim.x) {
    int ci = wk >> 3, oct = wk & 7;
    int r = candlist[ci];
    int row = origrow[r];
    float pd[16];
    proj_row8(x, W, row, l & 7, pd);                // bit-identical to project
    float t2 = 0.f, tm[16];
#pragma unroll
    for (int c = 0; c < 16; ++c) t2 = fmaf(pd[c], pd[c], t2);
#pragma unroll
    for (int c = 0; c < 16; ++c) tm[c] = -2.0f * pd[c];
    float minv = 3.4e38f; int mink = 0;
#pragma unroll 2
    for (int k = 0; k < 4; ++k) {                   // 4 codes/thread
      int code = oct * 1024 + k * 256 + tid;
      const float4* cp = (const float4*)(cbk + (long)code * CDIM);
      float4 c0 = cp[0], c1 = cp[1], c2v4 = cp[2], c3 = cp[3];
      float acc = fmaf(tm[0],  c0.x, c2[code]);
      acc = fmaf(tm[1],  c0.y, acc);   acc = fmaf(tm[2],  c0.z, acc);
      acc = fmaf(tm[3],  c0.w, acc);   acc = fmaf(tm[4],  c1.x, acc);
      acc = fmaf(tm[5],  c1.y, acc);   acc = fmaf(tm[6],  c1.z, acc);
      acc = fmaf(tm[7],  c1.w, acc);   acc = fmaf(tm[8],  c2v4.x, acc);
      acc = fmaf(tm[9],  c2v4.y, acc); acc = fmaf(tm[10], c2v4.z, acc);
      acc = fmaf(tm[11], c2v4.w, acc); acc = fmaf(tm[12], c3.x, acc);
      acc = fmaf(tm[13], c3.y, acc);   acc = fmaf(tm[14], c3.z, acc);
      acc = fmaf(tm[15], c3.w, acc);
      if (acc < minv) { minv = acc; mink = code; }
    }
    red[tid] = ((unsigned long long)encf(t2 + minv) << 32)
        | (unsigned long long)((unsigned int)r * (unsigned int)NCODES + (unsigned int)mink);
    __syncthreads();
    for (int s = 128; s > 0; s >>= 1) {
      if (tid < s) { if (red[tid + s] < red[tid]) red[tid] = red[tid + s]; }
      __syncthreads();
    }
    if (tid == 0) atomicMin(key, red[0]);
    __syncthreads();                                // LDS reuse across wk
  }
  if (tid == 0) {
    __threadfence();
    if (atomicAdd(resctr, 1u) == (unsigned int)gridDim.x - 1u) {
      unsigned long long v = atomicMin(key, 0xFFFFFFFFFFFFFFFFull);
      out[0] = (int)(unsigned int)(v & 0xFFFFFFFFull);
    }
  }
}

extern "C" void kernel_launch(void* const* d_in, const int* in_sizes, int n_in,
                              void* d_out, int out_size, void* d_ws, size_t ws_size,
                              hipStream_t stream) {
  const float* x    = (const float*)d_in[0];
  const int*   mask = (const int*)d_in[1];
  const float* W    = (const float*)d_in[2];
  const float* cbk  = (const float*)d_in[3];
  int* out = (int*)d_out;

  char* ws = (char*)d_ws;                                   // total 1,810,432 B
  int*                chunkpref = (int*)(ws + 2048);                // 2048
  unsigned int*       resctr    = (unsigned int*)(ws + 4100);       // 4
  unsigned int*       candcount = (unsigned int*)(ws + 4108);       // 4
  unsigned long long* key       = (unsigned long long*)(ws + 4112); // 8
  unsigned int*       c2max_u   = (unsigned int*)(ws + 4128);       // 4
  unsigned int*       rowmin_u  = (unsigned int*)(ws + 8192);       // 64 KiB
  float*              t2arr     = (float*)(ws + 73728);             // 64 KiB
  int*                origrow   = (int*)(ws + 139264);              // 64 KiB
  float*              c2        = (float*)(ws + 204800);            // 32 KiB
  unsigned short*     cbf32     = (unsigned short*)(ws + 237568);   // 512 KiB
  int*                candlist  = (int*)(ws + 237568);              // aliases cbf32 (dead by gate time)
  unsigned short*     tbf32     = (unsigned short*)(ws + 761856);   // 1 MiB

  hipMemsetAsync(ws + 4096, 0, 16, stream);                 // resctr (+spare)
  scan_kernel<<<1, 512, 0, stream>>>(mask, chunkpref, rowmin_u, key, c2max_u);
  project_kernel<<<1024, 256, 0, stream>>>(x, mask, chunkpref, W, cbk, c2, cbf32,
                                           tbf32, t2arr, origrow, c2max_u);
  phase1_kernel<<<2048, 256, 0, stream>>>(tbf32, cbf32, rowmin_u);
  gate_kernel<<<1, 1024, 0, stream>>>(rowmin_u, t2arr, c2max_u, candcount, candlist);
  rescore_kernel<<<128, 256, 0, stream>>>(x, W, cbk, c2, origrow, candcount,
                                          candlist, key, resctr, out);
}

// Round 10
// 112.063 us; speedup vs baseline: 2.3006x; 1.0681x over previous
//
#include <hip/hip_runtime.h>
#include <hip/hip_bf16.h>

// RandomProjectionQuantizer — MFMA screen + split candidate-proj/rescore (R10).
//  x:(16,2048,320) f32, mask:(16,2048) i32 (exactly 16384 ones),
//  W:(16,320) f32, codebook:(8192,16) f32 -> scalar int32 label
//
//  scan    : 1 block — chunk prefix scan, rowmin/key/c2max init.        (R9-verbatim)
//  project : 1024 blocks, 8 lanes/row + fused codebook fold conversion. (R9-verbatim)
//  phase1  : calibrated per-row MFMA screening.                         (R9-verbatim)
//  gate    : 1 block — T = min_r(a_r+eps_r), candidate list.            (R9-verbatim)
//  cproj   : exact f32 -2t for candidates only -> tgtm (reuses dead tbf32 region).
//  rescore : NO projection (no spill): uniform tgtm/t2 loads + 4 codes/thread.

#define NMASK   16384
#define D       320
#define CDIM    16
#define NCODES  8192
#define EPS_C   0.0117f      // 1.5 * 2^-7  (bf16 RNE dot-error coefficient)
#define EPS_ABS 0.02f

typedef __attribute__((ext_vector_type(8))) short short8;
typedef __attribute__((ext_vector_type(4))) float f32x4;

__device__ inline unsigned int encf(float f) {
  unsigned int u = __float_as_uint(f);
  return (u & 0x80000000u) ? ~u : (u | 0x80000000u);
}
__device__ inline float decf(unsigned int u) {
  unsigned int b = (u & 0x80000000u) ? (u & 0x7fffffffu) : ~u;
  return __uint_as_float(b);
}
__device__ inline unsigned short f2bf(float f) {   // RNE f32->bf16
  unsigned int u = __float_as_uint(f);
  unsigned int r = u + 0x7fffu + ((u >> 16) & 1u);
  return (unsigned short)(r >> 16);
}
__device__ inline float bf2f(unsigned short h) {
  return __uint_as_float(((unsigned int)h) << 16);
}

// projection: 8 lanes/row (chunk ch of 40 floats), butterfly combine (xor 1,2,4).
__device__ inline void proj_row8(const float* __restrict__ x,
                                 const float* __restrict__ W,
                                 int row, int ch, float pd[16]) {
#pragma unroll
  for (int c = 0; c < 16; ++c) pd[c] = 0.f;
  const float4* xp = (const float4*)(x + (size_t)row * D + ch * 40);
#pragma unroll
  for (int j = 0; j < 10; ++j) {
    float4 xv = xp[j];
#pragma unroll
    for (int c = 0; c < 16; ++c) {
      const float4 wv = *(const float4*)(W + c * D + ch * 40 + j * 4);
      float acc = fmaf(xv.x, wv.x, pd[c]);
      acc = fmaf(xv.y, wv.y, acc);
      acc = fmaf(xv.z, wv.z, acc);
      pd[c] = fmaf(xv.w, wv.w, acc);
    }
  }
#pragma unroll
  for (int c = 0; c < 16; ++c) {
    pd[c] += __shfl_xor(pd[c], 1);
    pd[c] += __shfl_xor(pd[c], 2);
    pd[c] += __shfl_xor(pd[c], 4);
  }
}

// ---------------- Kernel 1: scan (1 block x 512) -----------------------------
__global__ __launch_bounds__(512) void scan_kernel(
    const int* __restrict__ mask, int* __restrict__ chunkpref,
    unsigned int* __restrict__ rowmin_u, unsigned long long* __restrict__ key,
    unsigned int* __restrict__ c2max_u) {
  __shared__ int a[512], b[512];
  int tid = threadIdx.x;
  const int4* mp = (const int4*)(mask + tid * 64);   // thread-per-chunk
  int cnt = 0;
#pragma unroll
  for (int i = 0; i < 16; ++i) {
    int4 v = mp[i];
    cnt += (v.x != 0) + (v.y != 0) + (v.z != 0) + (v.w != 0);
  }
  a[tid] = cnt; __syncthreads();
  int *src = a, *dst = b;
  for (int off = 1; off < 512; off <<= 1) {          // Hillis-Steele inclusive
    dst[tid] = src[tid] + (tid >= off ? src[tid - off] : 0);
    __syncthreads();
    int* t = src; src = dst; dst = t;
  }
  chunkpref[tid] = (tid == 0) ? 0 : src[tid - 1];    // exclusive
  for (int i = tid; i < NMASK; i += 512) rowmin_u[i] = 0xFFFFFFFFu;
  if (tid == 0) { key[0] = 0xFFFFFFFFFFFFFFFFull; c2max_u[0] = 0u; }
}

// ---------------- Kernel 2: project (1024 blocks x 256) ----------------------
__global__ __launch_bounds__(256) void project_kernel(
    const float* __restrict__ x, const int* __restrict__ mask,
    const int* __restrict__ chunkpref, const float* __restrict__ W,
    const float* __restrict__ cbk, float* __restrict__ c2,
    unsigned short* __restrict__ cbf32, unsigned short* __restrict__ tbf32,
    float* __restrict__ t2arr, int* __restrict__ origrow,
    unsigned int* __restrict__ c2max_u) {
  __shared__ unsigned long long mb;
  int tid = threadIdx.x, bid = (int)blockIdx.x;
  int chunk = bid >> 1, half = bid & 1;
  if (tid < 64) {
    int m = mask[chunk * 64 + tid];
    unsigned long long bal = __ballot(m != 0);
    if (tid == 0) mb = bal;
  }
  __syncthreads();
  if (bid < 512 && tid < 16) {                       // fused codes job (R5 fold)
    int k = bid * 16 + tid;
    const float4* p = (const float4*)(cbk + (long)k * CDIM);
    float s = 0.f; unsigned short nb[16];
#pragma unroll
    for (int q = 0; q < 4; ++q) {
      float4 v = p[q];
      s = fmaf(v.x, v.x, s); s = fmaf(v.y, v.y, s);
      s = fmaf(v.z, v.z, s); s = fmaf(v.w, v.w, s);
      nb[q*4+0] = f2bf(-2.0f * v.x); nb[q*4+1] = f2bf(-2.0f * v.y);
      nb[q*4+2] = f2bf(-2.0f * v.z); nb[q*4+3] = f2bf(-2.0f * v.w);
    }
    c2[k] = s;
    atomicMax(c2max_u, __float_as_uint(s));          // s >= 0: bits monotone
    unsigned short g1 = f2bf(s);
    unsigned short g2 = f2bf(s - bf2f(g1));
    uint4 pk0, pk1, pk2, pk3;
    pk0.x = (unsigned int)nb[0]  | ((unsigned int)nb[1]  << 16);
    pk0.y = (unsigned int)nb[2]  | ((unsigned int)nb[3]  << 16);
    pk0.z = (unsigned int)nb[4]  | ((unsigned int)nb[5]  << 16);
    pk0.w = (unsigned int)nb[6]  | ((unsigned int)nb[7]  << 16);
    pk1.x = (unsigned int)nb[8]  | ((unsigned int)nb[9]  << 16);
    pk1.y = (unsigned int)nb[10] | ((unsigned int)nb[11] << 16);
    pk1.z = (unsigned int)nb[12] | ((unsigned int)nb[13] << 16);
    pk1.w = (unsigned int)nb[14] | ((unsigned int)nb[15] << 16);
    pk2.x = (unsigned int)g1 | ((unsigned int)g2 << 16); // dims 16,17: g1,g2
    pk2.y = 0x3F803F80u;                                 // dims 18,19: 1,1
    pk2.z = 0u; pk2.w = 0u;
    pk3.x = 0u; pk3.y = 0u; pk3.z = 0u; pk3.w = 0u;
    uint4* dst = (uint4*)(cbf32 + (long)k * 32);
    dst[0] = pk0; dst[1] = pk1; dst[2] = pk2; dst[3] = pk3;
  }
  unsigned long long B0 = mb;
  int r = tid >> 3, ch = tid & 7;
  int p = half * 32 + r;                             // bit position in chunk
  int row = chunk * 64 + p;
  if (!((B0 >> p) & 1ull)) return;
  float pd[16];
  proj_row8(x, W, row, ch, pd);
  if (ch == 0) {
    int rank = chunkpref[chunk] + __popcll(B0 & ((1ull << p) - 1ull));
    float t2 = 0.f;
#pragma unroll
    for (int c = 0; c < 16; ++c) t2 = fmaf(pd[c], pd[c], t2);
    t2arr[rank] = t2;
    origrow[rank] = row;
    unsigned short tb[16];
#pragma unroll
    for (int c = 0; c < 16; ++c) tb[c] = f2bf(pd[c]);
    unsigned short h1 = f2bf(t2);
    unsigned short h2 = f2bf(t2 - bf2f(h1));
    uint4 pk0, pk1, pk2, pk3;
    pk0.x = (unsigned int)tb[0]  | ((unsigned int)tb[1]  << 16);
    pk0.y = (unsigned int)tb[2]  | ((unsigned int)tb[3]  << 16);
    pk0.z = (unsigned int)tb[4]  | ((unsigned int)tb[5]  << 16);
    pk0.w = (unsigned int)tb[6]  | ((unsigned int)tb[7]  << 16);
    pk1.x = (unsigned int)tb[8]  | ((unsigned int)tb[9]  << 16);
    pk1.y = (unsigned int)tb[10] | ((unsigned int)tb[11] << 16);
    pk1.z = (unsigned int)tb[12] | ((unsigned int)tb[13] << 16);
    pk1.w = (unsigned int)tb[14] | ((unsigned int)tb[15] << 16);
    pk2.x = 0x3F803F80u;                                 // dims 16,17: 1,1
    pk2.y = (unsigned int)h1 | ((unsigned int)h2 << 16); // dims 18,19: h1,h2
    pk2.z = 0u; pk2.w = 0u;
    pk3.x = 0u; pk3.y = 0u; pk3.z = 0u; pk3.w = 0u;
    uint4* dst = (uint4*)(tbf32 + (long)rank * 32);
    dst[0] = pk0; dst[1] = pk1; dst[2] = pk2; dst[3] = pk3;
  }
}

// ---------------- Kernel 3: calibrated per-row MFMA screening (verbatim) -----
__global__ __launch_bounds__(256) void phase1_kernel(
    const unsigned short* __restrict__ tbf32,
    const unsigned short* __restrict__ cbf32,
    unsigned int* __restrict__ rowmin_u) {
  __shared__ unsigned int rml[4 * 33];
  int tid = threadIdx.x;
  int w = tid >> 6, l = tid & 63, lr = l & 15, g = l >> 4;
  int strip = (int)blockIdx.x >> 2;                 // 0..511
  int seg   = ((int)blockIdx.x & 3) * 4 + w;        // 0..15
  int row0 = strip * 32;

  for (int i = tid; i < 4 * 33; i += 256) rml[i] = 0xFFFFFFFFu;
  __syncthreads();

  const f32x4 zero = {0.f, 0.f, 0.f, 0.f};
  short8 calA = {0,0,0,0,0,0,0,0}, calB = {0,0,0,0,0,0,0,0};
  if (g == 0) {
    calA[0] = (short)f2bf((float)(lr + 1));
    calB[0] = (short)0x3F80;                        // bf16 1.0
  }
  f32x4 cal = __builtin_amdgcn_mfma_f32_16x16x32_bf16(calA, calB, zero, 0, 0, 0);
  int rid[4];
#pragma unroll
  for (int j = 0; j < 4; ++j) {
    int v = (int)(cal[j] + 0.5f) - 1;
    rid[j] = v < 0 ? 0 : (v > 15 ? 15 : v);
  }

  const short8 a0 = *(const short8*)(tbf32 + (long)(row0 + lr) * 32 + g * 8);
  const short8 a1 = *(const short8*)(tbf32 + (long)(row0 + 16 + lr) * 32 + g * 8);
  f32x4 rmin0 = {3.4e38f, 3.4e38f, 3.4e38f, 3.4e38f};
  f32x4 rmin1 = rmin0;
  int code0 = seg * 512;
#pragma unroll 2
  for (int t = 0; t < 32; ++t) {
    int code = code0 + t * 16 + lr;
    short8 b = *(const short8*)(cbf32 + (long)code * 32 + g * 8);
    f32x4 d0 = __builtin_amdgcn_mfma_f32_16x16x32_bf16(a0, b, zero, 0, 0, 0);
    f32x4 d1 = __builtin_amdgcn_mfma_f32_16x16x32_bf16(a1, b, zero, 0, 0, 0);
#pragma unroll
    for (int j = 0; j < 4; ++j) {
      rmin0[j] = fminf(rmin0[j], d0[j]);
      rmin1[j] = fminf(rmin1[j], d1[j]);
    }
  }
  unsigned int* mywave = &rml[w * 33];
#pragma unroll
  for (int j = 0; j < 4; ++j) {
    atomicMin(&mywave[rid[j]],      encf(rmin0[j]));
    atomicMin(&mywave[16 + rid[j]], encf(rmin1[j]));
  }
  __syncthreads();
  if (tid < 32) {
    unsigned int mn = 0xFFFFFFFFu;
#pragma unroll
    for (int ww = 0; ww < 4; ++ww) mn = min(mn, rml[ww * 33 + tid]);
    atomicMin(&rowmin_u[row0 + tid], mn);
  }
}

// ---------------- Kernel 4: gate (1 block x 1024) ----------------------------
__global__ __launch_bounds__(1024) void gate_kernel(
    const unsigned int* __restrict__ rowmin_u, const float* __restrict__ t2arr,
    const unsigned int* __restrict__ c2max_u,
    unsigned int* __restrict__ candcount, int* __restrict__ candlist) {
  __shared__ float sT[1024];
  __shared__ unsigned int cnt;
  int tid = threadIdx.x;
  float c2m = __uint_as_float(c2max_u[0]);
  float Tl = 3.4e38f;
  for (int i = tid; i < NMASK; i += 1024) {
    float a = decf(rowmin_u[i]);
    float e = fmaf(EPS_C, sqrtf(t2arr[i] * c2m), EPS_ABS);
    Tl = fminf(Tl, a + e);                          // NaN -> ignored
  }
  sT[tid] = Tl;
  if (tid == 0) cnt = 0u;
  __syncthreads();
  for (int st = 512; st > 0; st >>= 1) {
    if (tid < st) sT[tid] = fminf(sT[tid], sT[tid + st]);
    __syncthreads();
  }
  float T = sT[0];
  for (int i = tid; i < NMASK; i += 1024) {
    float a = decf(rowmin_u[i]);
    float e = fmaf(EPS_C, sqrtf(t2arr[i] * c2m), EPS_ABS);
    if (!(a - e > T)) {                             // NaN-safe: NaN -> candidate
      unsigned int pos = atomicAdd(&cnt, 1u);
      candlist[pos] = i;
    }
  }
  __syncthreads();
  if (tid == 0) candcount[0] = cnt;                 // plain store, no init needed
}

// ---------------- Kernel 5: cproj — exact f32 -2t for candidates only --------
// 8 lanes/row; writes tgtm[ci][16] (reuses dead tbf32 region). No other work in
// this kernel -> compiler keeps proj under ~128 VGPR, no spill interactions.
__global__ __launch_bounds__(256) void cproj_kernel(
    const float* __restrict__ x, const float* __restrict__ W,
    const int* __restrict__ origrow, const unsigned int* __restrict__ candcount,
    const int* __restrict__ candlist, float* __restrict__ tgtm) {
  int tid = threadIdx.x, bid = (int)blockIdx.x;
  int nc = (int)candcount[0];
  int ch = tid & 7;
  for (int idx = bid * 32 + (tid >> 3); idx < nc; idx += (int)gridDim.x * 32) {
    int row = origrow[candlist[idx]];
    float pd[16];
    proj_row8(x, W, row, ch, pd);
    if (ch == 0) {
      float* op = tgtm + (long)idx * 16;
#pragma unroll
      for (int c = 0; c < 16; ++c) op[c] = -2.0f * pd[c];
    }
  }
}

// ---------------- Kernel 6: rescore, block = (candidate, code-octant) --------
// No projection: tm/t2 are uniform (scalar) loads; 4 codes/thread; LDS reduce;
// u64 atomicMin merge; ticket-fused emit.
__global__ __launch_bounds__(256) void rescore_kernel(
    const float* __restrict__ cbk, const float* __restrict__ c2,
    const float* __restrict__ tgtm, const float* __restrict__ t2arr,
    const unsigned int* __restrict__ candcount, const int* __restrict__ candlist,
    unsigned long long* __restrict__ key, unsigned int* __restrict__ resctr,
    int* __restrict__ out) {
  __shared__ unsigned long long red[256];
  int tid = threadIdx.x, bid = (int)blockIdx.x;
  int nwork = (int)candcount[0] * 8;                // 8 octants x 1024 codes
  for (int wk = bid; wk < nwork; wk += (int)gridDim.x) {
    int ci = wk >> 3, oct = wk & 7;
    int r = candlist[ci];                           // uniform per block
    float t2 = t2arr[r];
    float tm[16];
    const float4* tp = (const float4*)(tgtm + (long)ci * 16);
#pragma unroll
    for (int q = 0; q < 4; ++q) {                   // uniform -> scalar loads
      float4 v = tp[q];
      tm[q*4+0] = v.x; tm[q*4+1] = v.y; tm[q*4+2] = v.z; tm[q*4+3] = v.w;
    }
    float minv = 3.4e38f; int mink = 0;
#pragma unroll 2
    for (int k = 0; k < 4; ++k) {                   // 4 codes/thread
      int code = oct * 1024 + k * 256 + tid;
      const float4* cp = (const float4*)(cbk + (long)code * CDIM);
      float4 c0 = cp[0], c1 = cp[1], c2v4 = cp[2], c3 = cp[3];
      float acc = fmaf(tm[0],  c0.x, c2[code]);
      acc = fmaf(tm[1],  c0.y, acc);   acc = fmaf(tm[2],  c0.z, acc);
      acc = fmaf(tm[3],  c0.w, acc);   acc = fmaf(tm[4],  c1.x, acc);
      acc = fmaf(tm[5],  c1.y, acc);   acc = fmaf(tm[6],  c1.z, acc);
      acc = fmaf(tm[7],  c1.w, acc);   acc = fmaf(tm[8],  c2v4.x, acc);
      acc = fmaf(tm[9],  c2v4.y, acc); acc = fmaf(tm[10], c2v4.z, acc);
      acc = fmaf(tm[11], c2v4.w, acc); acc = fmaf(tm[12], c3.x, acc);
      acc = fmaf(tm[13], c3.y, acc);   acc = fmaf(tm[14], c3.z, acc);
      acc = fmaf(tm[15], c3.w, acc);
      if (acc < minv) { minv = acc; mink = code; }
    }
    red[tid] = ((unsigned long long)encf(t2 + minv) << 32)
        | (unsigned long long)((unsigned int)r * (unsigned int)NCODES + (unsigned int)mink);
    __syncthreads();
    for (int s = 128; s > 0; s >>= 1) {
      if (tid < s) { if (red[tid + s] < red[tid]) red[tid] = red[tid + s]; }
      __syncthreads();
    }
    if (tid == 0) atomicMin(key, red[0]);
    __syncthreads();                                // LDS reuse across wk
  }
  if (tid == 0) {
    __threadfence();
    if (atomicAdd(resctr, 1u) == (unsigned int)gridDim.x - 1u) {
      unsigned long long v = atomicMin(key, 0xFFFFFFFFFFFFFFFFull);
      out[0] = (int)(unsigned int)(v & 0xFFFFFFFFull);
    }
  }
}

extern "C" void kernel_launch(void* const* d_in, const int* in_sizes, int n_in,
                              void* d_out, int out_size, void* d_ws, size_t ws_size,
                              hipStream_t stream) {
  const float* x    = (const float*)d_in[0];
  const int*   mask = (const int*)d_in[1];
  const float* W    = (const float*)d_in[2];
  const float* cbk  = (const float*)d_in[3];
  int* out = (int*)d_out;

  char* ws = (char*)d_ws;                                   // total 1,810,432 B
  int*                chunkpref = (int*)(ws + 2048);                // 2048
  unsigned int*       resctr    = (unsigned int*)(ws + 4100);       // 4
  unsigned int*       candcount = (unsigned int*)(ws + 4108);       // 4
  unsigned long long* key       = (unsigned long long*)(ws + 4112); // 8
  unsigned int*       c2max_u   = (unsigned int*)(ws + 4128);       // 4
  unsigned int*       rowmin_u  = (unsigned int*)(ws + 8192);       // 64 KiB
  float*              t2arr     = (float*)(ws + 73728);             // 64 KiB
  int*                origrow   = (int*)(ws + 139264);              // 64 KiB
  float*              c2        = (float*)(ws + 204800);            // 32 KiB
  unsigned short*     cbf32     = (unsigned short*)(ws + 237568);   // 512 KiB
  int*                candlist  = (int*)(ws + 237568);              // aliases cbf32 (dead by gate time)
  unsigned short*     tbf32     = (unsigned short*)(ws + 761856);   // 1 MiB
  float*              tgtm      = (float*)(ws + 761856);            // aliases tbf32 (dead after phase1)

  hipMemsetAsync(ws + 4096, 0, 16, stream);                 // resctr (+spare)
  scan_kernel<<<1, 512, 0, stream>>>(mask, chunkpref, rowmin_u, key, c2max_u);
  project_kernel<<<1024, 256, 0, stream>>>(x, mask, chunkpref, W, cbk, c2, cbf32,
                                           tbf32, t2arr, origrow, c2max_u);
  phase1_kernel<<<2048, 256, 0, stream>>>(tbf32, cbf32, rowmin_u);
  gate_kernel<<<1, 1024, 0, stream>>>(rowmin_u, t2arr, c2max_u, candcount, candlist);
  cproj_kernel<<<512, 256, 0, stream>>>(x, W, origrow, candcount, candlist, tgtm);
  rescore_kernel<<<512, 256, 0, stream>>>(cbk, c2, tgtm, t2arr, candcount,
                                          candlist, key, resctr, out);
}